// Round 10
// baseline (1132.128 us; speedup 1.0000x reference)
//
#include <hip/hip_runtime.h>
#include <hip/hip_bf16.h>
#include <math.h>

typedef unsigned short u16;
typedef __attribute__((ext_vector_type(4))) unsigned short us4;
typedef __attribute__((ext_vector_type(8))) unsigned short us8;
typedef __attribute__((ext_vector_type(8))) short s8v;   // mfma bf16 operand (4 VGPRs)
typedef __attribute__((ext_vector_type(4))) float f4v;   // mfma accum

#define BB 2
#define TT 1024
#define CC 2048
#define HH 32
#define BT (BB*TT)

// Inputs/outputs fp32. ws intermediates bf16: 7 regions x NBTC u16 = 56 MiB
// (ws_size >= that, established rounds 4/5/7). Weights cvt-transposed to bf16
// [N][K] just-in-time into dead regions for the MFMA GEMMs. Recurrence scalars
// (kr,br float2 per (b,t,h)) live in the back half of d_out's v0 slot.

__device__ __forceinline__ float bf2f(u16 u) {
  return __uint_as_float(((unsigned int)u) << 16);
}
__device__ __forceinline__ u16 f2bf(float f) {
  unsigned int x = __float_as_uint(f);
  x += 0x7fffu + ((x >> 16) & 1u);
  return (u16)(x >> 16);
}

// ---------------------------------------------------------------- mix kernel
__global__ __launch_bounds__(256)
void mix_k(const float* __restrict__ x, const float* __restrict__ s,
           u16* __restrict__ out) {
  int idx = blockIdx.x * 256 + threadIdx.x;       // over BT*C
  int c = idx & (CC - 1);
  int t = (idx >> 11) & (TT - 1);
  float xv = x[idx];
  float xp = (t == 0) ? 0.f : x[idx - CC];
  out[idx] = f2bf(xv + (xp - xv) * s[c]);
}

// ---------------------------------------------------------------- weight cvt-transpose
// W fp32 [K][N] -> Wt bf16 [N][K]. 32x32 tiles, 256 threads.
__global__ __launch_bounds__(256)
void wt_k(const float* __restrict__ W, u16* __restrict__ Wt, int K, int N) {
  __shared__ u16 tile[32][36];
  const int k0 = blockIdx.x * 32, n0 = blockIdx.y * 32;
  const int tid = threadIdx.x;
  const int r = tid >> 3, c4 = (tid & 7) << 2;
  float4 v = *(const float4*)(W + (size_t)(k0 + r) * N + n0 + c4);
  tile[r][c4 + 0] = f2bf(v.x); tile[r][c4 + 1] = f2bf(v.y);
  tile[r][c4 + 2] = f2bf(v.z); tile[r][c4 + 3] = f2bf(v.w);
  __syncthreads();
  ushort4 o;
  o.x = tile[c4 + 0][r]; o.y = tile[c4 + 1][r];
  o.z = tile[c4 + 2][r]; o.w = tile[c4 + 3][r];
  *(ushort4*)(Wt + (size_t)(n0 + r) * K + k0 + c4) = o;
}

// ---------------------------------------------------------------- MFMA GEMM
// C[M,N] = A[M,K](bf16, pitch K) * B(given as Bt[N][K] bf16), fp32 accum.
// Block tile 128x128, BK=32, 4 waves (2x2), wave tile 64x64 = 4x4 frags.
enum { EPI_BF = 0, EPI_F32 = 1, EPI_BIAS_SP = 2, EPI_BIAS_SIG = 3,
       EPI_VMIX = 4 };

template<int EPI>
__global__ __launch_bounds__(256)
void mgemm_k(const u16* __restrict__ A, const u16* __restrict__ Bt,
             float* __restrict__ outF, u16* __restrict__ outB,
             int M, int N, int K,
             const float* __restrict__ bias, const u16* __restrict__ p1,
             const float* __restrict__ p2)
{
  __shared__ alignas(16) u16 As[128][40];   // 32 k + 8 pad (80 B row stride)
  __shared__ alignas(16) u16 Bs[128][40];
  const int m0 = blockIdx.x * 128;
  const int n0 = blockIdx.y * 128;
  const int tid = threadIdx.x;
  const int lane = tid & 63;
  const int wid = tid >> 6;
  const int wr = wid >> 1, wc = wid & 1;        // wave quadrant (2x2)
  const int srow = tid >> 1;                    // staging row (0..127)
  const int scol = (tid & 1) << 4;              // staging k-col (0 or 16)
  f4v acc[4][4];
  #pragma unroll
  for (int i = 0; i < 4; ++i)
    #pragma unroll
    for (int j = 0; j < 4; ++j) acc[i][j] = f4v{0.f, 0.f, 0.f, 0.f};

  const int l15 = lane & 15;
  const int lk = (lane >> 4) << 3;              // k offset within BK (0,8,16,24)
  const int nkt = K >> 5;
  for (int kt = 0; kt < nkt; ++kt) {
    const int k0 = kt << 5;
    const u16* ap = A  + (size_t)(m0 + srow) * K + k0 + scol;
    const u16* bp = Bt + (size_t)(n0 + srow) * K + k0 + scol;
    us8 a0 = *(const us8*)(ap);
    us8 a1 = *(const us8*)(ap + 8);
    us8 b0 = *(const us8*)(bp);
    us8 b1 = *(const us8*)(bp + 8);
    __syncthreads();                            // prev compute done
    *(us8*)&As[srow][scol]     = a0;
    *(us8*)&As[srow][scol + 8] = a1;
    *(us8*)&Bs[srow][scol]     = b0;
    *(us8*)&Bs[srow][scol + 8] = b1;
    __syncthreads();
    s8v af[4], bfr[4];
    #pragma unroll
    for (int i = 0; i < 4; ++i)
      af[i] = *(const s8v*)&As[wr * 64 + i * 16 + l15][lk];
    #pragma unroll
    for (int j = 0; j < 4; ++j)
      bfr[j] = *(const s8v*)&Bs[wc * 64 + j * 16 + l15][lk];
    #pragma unroll
    for (int i = 0; i < 4; ++i)
      #pragma unroll
      for (int j = 0; j < 4; ++j)
        acc[i][j] = __builtin_amdgcn_mfma_f32_16x16x32_bf16(af[i], bfr[j],
                                                            acc[i][j], 0, 0, 0);
  }
  // C/D layout: col = lane&15, row = (lane>>4)*4 + q  (m89-verified)
  const int rbase = m0 + wr * 64 + ((lane >> 4) << 2);
  const int cbase = n0 + wc * 64 + l15;
  #pragma unroll
  for (int i = 0; i < 4; ++i) {
    #pragma unroll
    for (int j = 0; j < 4; ++j) {
      f4v c = acc[i][j];
      const int col = cbase + j * 16;
      #pragma unroll
      for (int q = 0; q < 4; ++q) {
        const int row = rbase + i * 16 + q;
        const size_t idx = (size_t)row * N + col;
        const float r = c[q];
        if (EPI == EPI_BF) {
          outB[idx] = f2bf(r);
        } else if (EPI == EPI_F32) {
          outF[idx] = r;
        } else if (EPI == EPI_BIAS_SP) {
          float u = bias[col] + r;
          float z = -u;
          float sp = fmaxf(z, 0.f) + log1pf(expf(-fabsf(z)));
          outB[idx] = f2bf(-sp - 0.5f);
        } else if (EPI == EPI_BIAS_SIG) {
          float u = bias[col] + r;
          outB[idx] = f2bf(1.f / (1.f + expf(-u)));
        } else if (EPI == EPI_VMIX) {
          float u = bias[col] + r;
          float sg = 1.f / (1.f + expf(-u));
          float v = bf2f(p1[idx]);
          float v0v = p2[idx];
          outB[idx] = f2bf(v + (v0v - v) * sg);
        }
      }
    }
  }
}

// ---------------------------------------------------------------- SIMT GEMM (skinny w1 paths)
__global__ __launch_bounds__(256)
void gemm_part_k(const u16* __restrict__ A, const float* __restrict__ W,
                 float* __restrict__ outF, int M, int N, int K, int kchunk,
                 int NP)
{
  __shared__ alignas(16) float As[16][68];
  __shared__ alignas(16) float Bs[16][68];
  const int m0 = blockIdx.x * 64;
  const int n0 = blockIdx.y * 64;
  const int kz = blockIdx.z;
  const int k0base = kz * kchunk;
  const int tid = threadIdx.x;
  const int tx = tid & 15, ty = tid >> 4;
  float acc[4][4] = {{0.f}};
  const int a_m = tid >> 2;
  const int a_k = (tid & 3) << 2;
  const int b_k = tid >> 4;
  const int b_n = (tid & 15) << 2;
  const int niters = kchunk >> 4;
  for (int it = 0; it < niters; ++it) {
    const int k0 = k0base + (it << 4);
    float4 av;
    {
      ushort4 u = *(const ushort4*)(A + (size_t)(m0 + a_m) * K + (k0 + a_k));
      av = make_float4(bf2f(u.x), bf2f(u.y), bf2f(u.z), bf2f(u.w));
    }
    float4 bv;
    {
      int gn = n0 + b_n;
      const float* wp = W + (size_t)(k0 + b_k) * N + gn;
      if (gn + 3 < N) {
        bv = *(const float4*)wp;
      } else {
        bv.x = (gn + 0 < N) ? wp[0] : 0.f;
        bv.y = (gn + 1 < N) ? wp[1] : 0.f;
        bv.z = (gn + 2 < N) ? wp[2] : 0.f;
        bv.w = (gn + 3 < N) ? wp[3] : 0.f;
      }
    }
    __syncthreads();
    As[a_k + 0][a_m] = av.x; As[a_k + 1][a_m] = av.y;
    As[a_k + 2][a_m] = av.z; As[a_k + 3][a_m] = av.w;
    Bs[b_k][b_n + 0] = bv.x; Bs[b_k][b_n + 1] = bv.y;
    Bs[b_k][b_n + 2] = bv.z; Bs[b_k][b_n + 3] = bv.w;
    __syncthreads();
    #pragma unroll
    for (int kk = 0; kk < 16; ++kk) {
      float4 a4 = *(const float4*)&As[kk][ty << 2];
      float4 b4 = *(const float4*)&Bs[kk][tx << 2];
      float ar[4] = {a4.x, a4.y, a4.z, a4.w};
      float br[4] = {b4.x, b4.y, b4.z, b4.w};
      #pragma unroll
      for (int i = 0; i < 4; ++i)
        #pragma unroll
        for (int j = 0; j < 4; ++j)
          acc[i][j] = fmaf(ar[i], br[j], acc[i][j]);
    }
  }
  #pragma unroll
  for (int i = 0; i < 4; ++i) {
    int gm = m0 + (ty << 2) + i;
    #pragma unroll
    for (int j = 0; j < 4; ++j) {
      int gn = n0 + (tx << 2) + j;
      if (gn >= N) continue;
      outF[((size_t)kz * M + gm) * NP + gn] = acc[i][j];
    }
  }
}

// ---------------------------------------------------------------- K-split reduce
__global__ __launch_bounds__(256)
void reduce_k(const float* __restrict__ part, u16* __restrict__ out,
              int M, int D, int NP, int nz, int act)
{
  int idx = blockIdx.x * 256 + threadIdx.x;
  if (idx >= M * D) return;
  int t = idx / D, n = idx - t * D;
  float s = 0.f;
  for (int z = 0; z < nz; ++z) s += part[((size_t)z * M + t) * NP + n];
  if (act == 1) s = tanhf(s);
  else if (act == 2) s = 1.f / (1.f + expf(-s));
  out[idx] = f2bf(s);
}

// ---------------------------------------------------------------- recurrence prep
// Per (b,t,h) wave (lane = j): from k, a, r, w_raw compute
//   kkn = normalize(k*kk_s);  ao=-kkn;  bo=kkn*a;  kf=k*(1+(a-1)*ka_s);
//   wd = exp(-exp(w_raw));    rw = wd*r;
//   scal2[hidx] = (kr, br) = (sum_j kf*r, sum_j bo*r)  fp32
__global__ __launch_bounds__(256)
void prep_k(const u16* __restrict__ k_in, const u16* __restrict__ a_in,
            const u16* __restrict__ r_in, const u16* __restrict__ w_in,
            const float* __restrict__ kk_s, const float* __restrict__ ka_s,
            u16* __restrict__ ao_out, u16* __restrict__ bo_out,
            u16* __restrict__ k_out, u16* __restrict__ wd_out,
            u16* __restrict__ rw_out, float2* __restrict__ scal)
{
  int tid = threadIdx.x;
  int lane = tid & 63;
  int wv = tid >> 6;
  int hidx = blockIdx.x * 4 + wv;               // (b*T+t)*H + h
  int h = hidx & (HH - 1);
  int c = (h << 6) + lane;
  size_t base = ((size_t)hidx << 6) + lane;
  float k = bf2f(k_in[base]);
  float kk = k * kk_s[c];
  float ss = kk * kk;
  for (int off = 32; off; off >>= 1) ss += __shfl_xor(ss, off, 64);
  float kkn = kk / fmaxf(sqrtf(ss), 1e-12f);
  float a = bf2f(a_in[base]);
  float r = bf2f(r_in[base]);
  float kf = k * (1.f + (a - 1.f) * ka_s[c]);
  float wd = expf(-expf(bf2f(w_in[base])));
  float bo = kkn * a;
  ao_out[base] = f2bf(-kkn);
  bo_out[base] = f2bf(bo);
  k_out[base]  = f2bf(kf);
  wd_out[base] = f2bf(wd);
  rw_out[base] = f2bf(wd * r);
  float kr = kf * r, br = bo * r;
  kr += __shfl_xor(kr, 1, 64);  br += __shfl_xor(br, 1, 64);
  kr += __shfl_xor(kr, 2, 64);  br += __shfl_xor(br, 2, 64);
  kr += __shfl_xor(kr, 4, 64);  br += __shfl_xor(br, 4, 64);
  kr += __shfl_xor(kr, 8, 64);  br += __shfl_xor(br, 8, 64);
  kr += __shfl_xor(kr, 16, 64); br += __shfl_xor(br, 16, 64);
  kr += __shfl_xor(kr, 32, 64); br += __shfl_xor(br, 32, 64);
  if (lane == 0) scal[hidx] = make_float2(kr, br);
}

// ---------------------------------------------------------------- RWKV7 recurrence
// g=16 geometry (R9) + 4-deep software pipeline (this round): four named
// prefetch register sets A..D; each step converts its set to locals,
// re-issues that set's loads for t+4 (covering ~3-4 step-chains of latency),
// then computes. Loop unrolled x4 so all set indices are compile-time.
__global__ __launch_bounds__(256)
void rec_k(const u16* __restrict__ rw, const u16* __restrict__ wd,
           const u16* __restrict__ kv, const u16* __restrict__ v,
           const u16* __restrict__ ao, const u16* __restrict__ bo,
           const float2* __restrict__ scal, u16* __restrict__ y)
{
  const int gw = blockIdx.x * 4 + (threadIdx.x >> 6);   // 0..1023
  const int lane = threadIdx.x & 63;
  const int sub = lane & 15;                    // j-subgroup within row
  const int grp = lane >> 4;                    // row within wave's 4-row block
  const int bh = gw >> 4;                       // 0..63
  const int rblk = gw & 15;
  const int i = rblk * 4 + grp;                 // value-dim row
  const int b = bh >> 5, h = bh & (HH - 1);
  const size_t base0 = ((size_t)b * TT) * CC + (h << 6);
  const size_t vecb = base0 + (sub << 2);       // j-vector base (us4)
  const size_t vb   = base0 + i;                // v, y
  const int sbase = b * TT * HH + h;            // + t*HH
  float s0 = 0.f, s1 = 0.f, s2 = 0.f, s3 = 0.f;

#define RLOAD(T, W_, K_, A_, B_, R_, V_, S_) do {                       \
    const size_t nb_ = vecb + (size_t)(T) * CC;                         \
    W_ = *(const us4*)(wd + nb_);                                       \
    K_ = *(const us4*)(kv + nb_);                                       \
    A_ = *(const us4*)(ao + nb_);                                       \
    B_ = *(const us4*)(bo + nb_);                                       \
    R_ = *(const us4*)(rw + nb_);                                       \
    V_ = bf2f(v[vb + (size_t)(T) * CC]);                                \
    S_ = scal[sbase + (T) * HH];                                        \
  } while (0)

  us4 wdA, kA, aoA, boA, rwA; float vA; float2 sA;
  us4 wdB, kB, aoB, boB, rwB; float vB; float2 sB;
  us4 wdC, kC, aoC, boC, rwC; float vC; float2 sC;
  us4 wdD, kD, aoD, boD, rwD; float vD; float2 sD;
  RLOAD(0, wdA, kA, aoA, boA, rwA, vA, sA);
  RLOAD(1, wdB, kB, aoB, boB, rwB, vB, sB);
  RLOAD(2, wdC, kC, aoC, boC, rwC, vC, sC);
  RLOAD(3, wdD, kD, aoD, boD, rwD, vD, sD);

#define RSTEP(T, W_, K_, A_, B_, R_, V_, S_) do {                       \
    const float w0 = bf2f(W_[0]), w1 = bf2f(W_[1]),                     \
                w2 = bf2f(W_[2]), w3 = bf2f(W_[3]);                     \
    const float q0 = bf2f(K_[0]), q1 = bf2f(K_[1]),                     \
                q2 = bf2f(K_[2]), q3 = bf2f(K_[3]);                     \
    const float a0 = bf2f(A_[0]), a1 = bf2f(A_[1]),                     \
                a2 = bf2f(A_[2]), a3 = bf2f(A_[3]);                     \
    const float c0 = bf2f(B_[0]), c1 = bf2f(B_[1]),                     \
                c2 = bf2f(B_[2]), c3 = bf2f(B_[3]);                     \
    const float e0 = bf2f(R_[0]), e1 = bf2f(R_[1]),                     \
                e2 = bf2f(R_[2]), e3 = bf2f(R_[3]);                     \
    const float cv = V_, ckr = S_.x, cbr = S_.y;                        \
    if ((T) + 4 < TT) RLOAD((T) + 4, W_, K_, A_, B_, R_, V_, S_);       \
    float sa = fmaf(s3, a3, fmaf(s2, a2, fmaf(s1, a1, s0 * a0)));       \
    float yw = fmaf(s3, e3, fmaf(s2, e2, fmaf(s1, e1, s0 * e0)));       \
    sa += __shfl_xor(sa, 1, 64);  yw += __shfl_xor(yw, 1, 64);          \
    sa += __shfl_xor(sa, 2, 64);  yw += __shfl_xor(yw, 2, 64);          \
    sa += __shfl_xor(sa, 4, 64);  yw += __shfl_xor(yw, 4, 64);          \
    sa += __shfl_xor(sa, 8, 64);  yw += __shfl_xor(yw, 8, 64);          \
    s0 = fmaf(cv, q0, fmaf(sa, c0, s0 * w0));                           \
    s1 = fmaf(cv, q1, fmaf(sa, c1, s1 * w1));                           \
    s2 = fmaf(cv, q2, fmaf(sa, c2, s2 * w2));                           \
    s3 = fmaf(cv, q3, fmaf(sa, c3, s3 * w3));                           \
    float o = fmaf(cv, ckr, fmaf(sa, cbr, yw));                         \
    if (sub == 0) y[vb + (size_t)(T) * CC] = f2bf(o);                   \
  } while (0)

  for (int t = 0; t < TT; t += 4) {
    RSTEP(t + 0, wdA, kA, aoA, boA, rwA, vA, sA);
    RSTEP(t + 1, wdB, kB, aoB, boB, rwB, vB, sB);
    RSTEP(t + 2, wdC, kC, aoC, boC, rwC, vC, sC);
    RSTEP(t + 3, wdD, kD, aoD, boD, rwD, vD, sD);
  }
#undef RLOAD
#undef RSTEP
}

// ---------------------------------------------------------------- GroupNorm + bonus + gate
__global__ __launch_bounds__(256)
void gn_k(u16* __restrict__ y, const u16* __restrict__ r,
          const u16* __restrict__ k, const u16* __restrict__ v,
          const u16* __restrict__ g, const float* __restrict__ rk_s,
          const float* __restrict__ gn_w, const float* __restrict__ gn_b)
{
  int tid = threadIdx.x, lane = tid & 63, wv = tid >> 6;
  int hidx = blockIdx.x * 4 + wv;
  int h = hidx & (HH - 1);
  int c = (h << 6) + lane;
  size_t base = ((size_t)hidx << 6) + lane;
  float yv = bf2f(y[base]), rv = bf2f(r[base]), kv = bf2f(k[base]);
  float vv = bf2f(v[base]), gv = bf2f(g[base]);
  float bsum = rv * kv * rk_s[c];
  float s1 = yv, s2 = yv * yv;
  for (int off = 32; off; off >>= 1) {
    s1 += __shfl_xor(s1, off, 64);
    s2 += __shfl_xor(s2, off, 64);
    bsum += __shfl_xor(bsum, off, 64);
  }
  float mu = s1 * (1.f / 64.f);
  float var = s2 * (1.f / 64.f) - mu * mu;
  float rstd = rsqrtf(var + 0.00064f);
  float z = (yv - mu) * rstd * gn_w[c] + gn_b[c];
  y[base] = f2bf((z + bsum * vv) * gv);
}

// ---------------------------------------------------------------- helpers
__global__ __launch_bounds__(256)
void copy_v0(const float* __restrict__ v0, float* __restrict__ out) {
  int idx = blockIdx.x * 256 + threadIdx.x;
  ((float4*)out)[idx] = ((const float4*)v0)[idx];
}

__global__ __launch_bounds__(256)
void zero_out(float* __restrict__ out) {
  int idx = blockIdx.x * 256 + threadIdx.x;
  ((float4*)out)[idx] = make_float4(0.f, 0.f, 0.f, 0.f);
}

// ----------------------------------------------------------------
extern "C" void kernel_launch(void* const* d_in, const int* in_sizes, int n_in,
                              void* d_out, int out_size, void* d_ws, size_t ws_size,
                              hipStream_t stream) {
  (void)n_in; (void)out_size;
  const bool dictOrder = (in_sizes[9] == CC);
  int IX[28];
  if (dictOrder) {
    const int m[28] = {0,1,2,3,4,5,6,7, 8,13,14, 9,15,16, 10,17,18, 19,20,
                       11,12,21, 22,23,24,25, 26,27};
    for (int i = 0; i < 28; ++i) IX[i] = m[i];
  } else {
    for (int i = 0; i < 28; ++i) IX[i] = i;
  }
  const float* x     = (const float*)d_in[IX[0]];
  const float* v0    = (const float*)d_in[IX[1]];
  const float* xx_r  = (const float*)d_in[IX[2]];
  const float* xx_w  = (const float*)d_in[IX[3]];
  const float* xx_k  = (const float*)d_in[IX[4]];
  const float* xx_v  = (const float*)d_in[IX[5]];
  const float* xx_a  = (const float*)d_in[IX[6]];
  const float* xx_g  = (const float*)d_in[IX[7]];
  const float* ww_b  = (const float*)d_in[IX[8]];
  const float* ww_w1 = (const float*)d_in[IX[9]];
  const float* ww_w2 = (const float*)d_in[IX[10]];
  const float* aa_b  = (const float*)d_in[IX[11]];
  const float* aa_w1 = (const float*)d_in[IX[12]];
  const float* aa_w2 = (const float*)d_in[IX[13]];
  const float* vv_b  = (const float*)d_in[IX[14]];
  const float* vv_w1 = (const float*)d_in[IX[15]];
  const float* vv_w2 = (const float*)d_in[IX[16]];
  const float* gg_w1 = (const float*)d_in[IX[17]];
  const float* gg_w2 = (const float*)d_in[IX[18]];
  const float* kk_s  = (const float*)d_in[IX[19]];
  const float* ka_s  = (const float*)d_in[IX[20]];
  const float* rk_s  = (const float*)d_in[IX[21]];
  const float* W_r   = (const float*)d_in[IX[22]];
  const float* W_k   = (const float*)d_in[IX[23]];
  const float* W_v   = (const float*)d_in[IX[24]];
  const float* W_o   = (const float*)d_in[IX[25]];
  const float* gn_w  = (const float*)d_in[IX[26]];
  const float* gn_b  = (const float*)d_in[IX[27]];

  const size_t NBTC = (size_t)BT * CC;      // 4,194,304 elements (8 MiB bf16)
  dim3 blk(256);
  const int grid4f = (int)(NBTC / 4 / 256);

  const size_t WS_NEED = 7 * NBTC * sizeof(u16);
  float* outF = (float*)d_out;
  if (ws_size < WS_NEED || d_ws == nullptr) {
    zero_out<<<grid4f, blk, 0, stream>>>(outF);
    copy_v0<<<grid4f, blk, 0, stream>>>(v0, outF + NBTC);
    return;
  }

  // Regions: R0=h1/r  R1=Wt(early)/k  R2=v  R3=partY/Wt/ao/h2
  // R4=a/bo/g  R5=w_raw/wd -> partG/Wt(g,o)  R6=mix staging/rw.
  // y (bf16) in d_out v0-slot front half; kr/br float2 in its back half.
  u16* W16   = (u16*)d_ws;
  u16* R0 = W16 + 0 * NBTC;
  u16* R1 = W16 + 1 * NBTC;
  u16* R2 = W16 + 2 * NBTC;
  u16* R3 = W16 + 3 * NBTC;
  u16* R4 = W16 + 4 * NBTC;
  u16* R5 = W16 + 5 * NBTC;
  u16* R6 = W16 + 6 * NBTC;
  float* partY = (float*)R3;
  float* partG = (float*)R5;
  u16* ws_y = (u16*)(outF + NBTC);          // bf16 y: front half of v0 slot
  float2* scal = (float2*)(ws_y + NBTC);    // kr/br: 512 KB in back half

  const int gridMix = (BT * CC) / 256;
  dim3 gM(BT / 128, 2048 / 128);            // (16, 16)

  // ---- w path
  mix_k<<<gridMix, blk, 0, stream>>>(x, xx_w, R6);
  gemm_part_k<<<dim3(32, 2, 8), blk, 0, stream>>>(R6, ww_w1, partY,
      BT, 96, 2048, 256, 128);
  reduce_k<<<(BT * 96 + 255) / 256, blk, 0, stream>>>(partY, R0, BT, 96, 128, 8, 1);
  wt_k<<<dim3(3, 64), blk, 0, stream>>>(ww_w2, R1, 96, 2048);
  mgemm_k<EPI_BIAS_SP><<<gM, blk, 0, stream>>>(R0, R1, nullptr, R5,
      BT, 2048, 96, ww_b, nullptr, nullptr);

  // ---- a path
  mix_k<<<gridMix, blk, 0, stream>>>(x, xx_a, R6);
  gemm_part_k<<<dim3(32, 2, 8), blk, 0, stream>>>(R6, aa_w1, partY,
      BT, 96, 2048, 256, 128);
  reduce_k<<<(BT * 96 + 255) / 256, blk, 0, stream>>>(partY, R0, BT, 96, 128, 8, 0);
  wt_k<<<dim3(3, 64), blk, 0, stream>>>(aa_w2, R1, 96, 2048);
  mgemm_k<EPI_BIAS_SIG><<<gM, blk, 0, stream>>>(R0, R1, nullptr, R4,
      BT, 2048, 96, aa_b, nullptr, nullptr);

  // ---- v path
  mix_k<<<gridMix, blk, 0, stream>>>(x, xx_v, R6);
  wt_k<<<dim3(64, 64), blk, 0, stream>>>(W_v, R1, 2048, 2048);
  mgemm_k<EPI_BF><<<gM, blk, 0, stream>>>(R6, R1, nullptr, R2,
      BT, 2048, 2048, nullptr, nullptr, nullptr);
  gemm_part_k<<<dim3(32, 1, 8), blk, 0, stream>>>(R6, vv_w1, partY,
      BT, 64, 2048, 256, 64);
  reduce_k<<<(BT * 64 + 255) / 256, blk, 0, stream>>>(partY, R0, BT, 64, 64, 8, 0);
  wt_k<<<dim3(2, 64), blk, 0, stream>>>(vv_w2, R1, 64, 2048);
  mgemm_k<EPI_VMIX><<<gM, blk, 0, stream>>>(R0, R1, nullptr, R2,
      BT, 2048, 64, vv_b, R2, v0);

  // ---- k path
  mix_k<<<gridMix, blk, 0, stream>>>(x, xx_k, R6);
  wt_k<<<dim3(64, 64), blk, 0, stream>>>(W_k, R3, 2048, 2048);
  mgemm_k<EPI_BF><<<gM, blk, 0, stream>>>(R6, R3, nullptr, R1,
      BT, 2048, 2048, nullptr, nullptr, nullptr);

  // ---- r path
  mix_k<<<gridMix, blk, 0, stream>>>(x, xx_r, R6);
  wt_k<<<dim3(64, 64), blk, 0, stream>>>(W_r, R3, 2048, 2048);
  mgemm_k<EPI_BF><<<gM, blk, 0, stream>>>(R6, R3, nullptr, R0,
      BT, 2048, 2048, nullptr, nullptr, nullptr);

  // ---- recurrence prep: k(R1),a(R4),r(R0),w_raw(R5) ->
  //      ao(R3), bo(R4), kf(R1), wd(R5), rw(R6), scal
  prep_k<<<BT * HH / 4, blk, 0, stream>>>(R1, R4, R0, R5, kk_s, ka_s,
                                          R3, R4, R1, R5, R6, scal);

  // ---- recurrence (g=16, 4-deep pipeline): rw=R6 wd=R5 k=R1 v=R2 ao=R3 bo=R4
  rec_k<<<256, blk, 0, stream>>>(R6, R5, R1, R2, R3, R4, scal, ws_y);

  // ---- g path (R5, R3, R4, R6 dead after rec)
  mix_k<<<gridMix, blk, 0, stream>>>(x, xx_g, R6);
  gemm_part_k<<<dim3(32, 4, 2), blk, 0, stream>>>(R6, gg_w1, partG,
      BT, 256, 2048, 1024, 256);
  reduce_k<<<(BT * 256 + 255) / 256, blk, 0, stream>>>(partG, R3, BT, 256, 256, 2, 2);
  wt_k<<<dim3(8, 64), blk, 0, stream>>>(gg_w2, R5, 256, 2048);
  mgemm_k<EPI_BF><<<gM, blk, 0, stream>>>(R3, R5, nullptr, R4,
      BT, 2048, 256, nullptr, nullptr, nullptr);

  // ---- groupnorm + bonus + gate (in place on y)
  gn_k<<<BT * HH / 4, blk, 0, stream>>>(ws_y, R0, R1, R2, R4,
                                        rk_s, gn_w, gn_b);

  // ---- final projection y @ W_o -> fp32 output 0
  wt_k<<<dim3(64, 64), blk, 0, stream>>>(W_o, R5, 2048, 2048);
  mgemm_k<EPI_F32><<<gM, blk, 0, stream>>>(ws_y, R5, outF, nullptr,
      BT, 2048, 2048, nullptr, nullptr, nullptr);

  // ---- v0 passthrough (overwrites y scratch + scal, last)
  copy_v0<<<grid4f, blk, 0, stream>>>(v0, outF + NBTC);
}

// Round 11
// 973.899 us; speedup vs baseline: 1.1625x; 1.1625x over previous
//
#include <hip/hip_runtime.h>
#include <hip/hip_bf16.h>
#include <math.h>

typedef unsigned short u16;
typedef __attribute__((ext_vector_type(2))) unsigned short us2;
typedef __attribute__((ext_vector_type(8))) unsigned short us8;
typedef __attribute__((ext_vector_type(8))) short s8v;   // mfma bf16 operand (4 VGPRs)
typedef __attribute__((ext_vector_type(4))) float f4v;   // mfma accum

#define BB 2
#define TT 1024
#define CC 2048
#define HH 32
#define BT (BB*TT)

// Inputs/outputs fp32. ws intermediates bf16: 7 regions x NBTC u16
// (ws_size >= that, established rounds 4/5/7). Weights cvt-transposed to bf16
// [N][K] just-in-time into dead regions for the MFMA GEMMs. Recurrence scalars
// (kr,br float2 per (b,t,h)) live in the back half of d_out's v0 slot.

__device__ __forceinline__ float bf2f(u16 u) {
  return __uint_as_float(((unsigned int)u) << 16);
}
__device__ __forceinline__ u16 f2bf(float f) {
  unsigned int x = __float_as_uint(f);
  x += 0x7fffu + ((x >> 16) & 1u);
  return (u16)(x >> 16);
}

// ---------------------------------------------------------------- mix kernel
__global__ __launch_bounds__(256)
void mix_k(const float* __restrict__ x, const float* __restrict__ s,
           u16* __restrict__ out) {
  int idx = blockIdx.x * 256 + threadIdx.x;       // over BT*C
  int c = idx & (CC - 1);
  int t = (idx >> 11) & (TT - 1);
  float xv = x[idx];
  float xp = (t == 0) ? 0.f : x[idx - CC];
  out[idx] = f2bf(xv + (xp - xv) * s[c]);
}

// ---------------------------------------------------------------- weight cvt-transpose
// W fp32 [K][N] -> Wt bf16 [N][K]. 32x32 tiles, 256 threads.
__global__ __launch_bounds__(256)
void wt_k(const float* __restrict__ W, u16* __restrict__ Wt, int K, int N) {
  __shared__ u16 tile[32][36];
  const int k0 = blockIdx.x * 32, n0 = blockIdx.y * 32;
  const int tid = threadIdx.x;
  const int r = tid >> 3, c4 = (tid & 7) << 2;
  float4 v = *(const float4*)(W + (size_t)(k0 + r) * N + n0 + c4);
  tile[r][c4 + 0] = f2bf(v.x); tile[r][c4 + 1] = f2bf(v.y);
  tile[r][c4 + 2] = f2bf(v.z); tile[r][c4 + 3] = f2bf(v.w);
  __syncthreads();
  ushort4 o;
  o.x = tile[c4 + 0][r]; o.y = tile[c4 + 1][r];
  o.z = tile[c4 + 2][r]; o.w = tile[c4 + 3][r];
  *(ushort4*)(Wt + (size_t)(n0 + r) * K + k0 + c4) = o;
}

// ---------------------------------------------------------------- MFMA GEMM
// C[M,N] = A[M,K](bf16, pitch K) * B(given as Bt[N][K] bf16), fp32 accum.
// Block tile 128x128, BK=32, 4 waves (2x2), wave tile 64x64 = 4x4 frags.
enum { EPI_BF = 0, EPI_F32 = 1, EPI_BIAS_SP = 2, EPI_BIAS_SIG = 3,
       EPI_VMIX = 4 };

template<int EPI>
__global__ __launch_bounds__(256)
void mgemm_k(const u16* __restrict__ A, const u16* __restrict__ Bt,
             float* __restrict__ outF, u16* __restrict__ outB,
             int M, int N, int K,
             const float* __restrict__ bias, const u16* __restrict__ p1,
             const float* __restrict__ p2)
{
  __shared__ alignas(16) u16 As[128][40];   // 32 k + 8 pad (80 B row stride)
  __shared__ alignas(16) u16 Bs[128][40];
  const int m0 = blockIdx.x * 128;
  const int n0 = blockIdx.y * 128;
  const int tid = threadIdx.x;
  const int lane = tid & 63;
  const int wid = tid >> 6;
  const int wr = wid >> 1, wc = wid & 1;        // wave quadrant (2x2)
  const int srow = tid >> 1;                    // staging row (0..127)
  const int scol = (tid & 1) << 4;              // staging k-col (0 or 16)
  f4v acc[4][4];
  #pragma unroll
  for (int i = 0; i < 4; ++i)
    #pragma unroll
    for (int j = 0; j < 4; ++j) acc[i][j] = f4v{0.f, 0.f, 0.f, 0.f};

  const int l15 = lane & 15;
  const int lk = (lane >> 4) << 3;              // k offset within BK (0,8,16,24)
  const int nkt = K >> 5;
  for (int kt = 0; kt < nkt; ++kt) {
    const int k0 = kt << 5;
    const u16* ap = A  + (size_t)(m0 + srow) * K + k0 + scol;
    const u16* bp = Bt + (size_t)(n0 + srow) * K + k0 + scol;
    us8 a0 = *(const us8*)(ap);
    us8 a1 = *(const us8*)(ap + 8);
    us8 b0 = *(const us8*)(bp);
    us8 b1 = *(const us8*)(bp + 8);
    __syncthreads();                            // prev compute done
    *(us8*)&As[srow][scol]     = a0;
    *(us8*)&As[srow][scol + 8] = a1;
    *(us8*)&Bs[srow][scol]     = b0;
    *(us8*)&Bs[srow][scol + 8] = b1;
    __syncthreads();
    s8v af[4], bfr[4];
    #pragma unroll
    for (int i = 0; i < 4; ++i)
      af[i] = *(const s8v*)&As[wr * 64 + i * 16 + l15][lk];
    #pragma unroll
    for (int j = 0; j < 4; ++j)
      bfr[j] = *(const s8v*)&Bs[wc * 64 + j * 16 + l15][lk];
    #pragma unroll
    for (int i = 0; i < 4; ++i)
      #pragma unroll
      for (int j = 0; j < 4; ++j)
        acc[i][j] = __builtin_amdgcn_mfma_f32_16x16x32_bf16(af[i], bfr[j],
                                                            acc[i][j], 0, 0, 0);
  }
  // C/D layout: col = lane&15, row = (lane>>4)*4 + q  (m89-verified)
  const int rbase = m0 + wr * 64 + ((lane >> 4) << 2);
  const int cbase = n0 + wc * 64 + l15;
  #pragma unroll
  for (int i = 0; i < 4; ++i) {
    #pragma unroll
    for (int j = 0; j < 4; ++j) {
      f4v c = acc[i][j];
      const int col = cbase + j * 16;
      #pragma unroll
      for (int q = 0; q < 4; ++q) {
        const int row = rbase + i * 16 + q;
        const size_t idx = (size_t)row * N + col;
        const float r = c[q];
        if (EPI == EPI_BF) {
          outB[idx] = f2bf(r);
        } else if (EPI == EPI_F32) {
          outF[idx] = r;
        } else if (EPI == EPI_BIAS_SP) {
          float u = bias[col] + r;
          float z = -u;
          float sp = fmaxf(z, 0.f) + log1pf(expf(-fabsf(z)));
          outB[idx] = f2bf(-sp - 0.5f);
        } else if (EPI == EPI_BIAS_SIG) {
          float u = bias[col] + r;
          outB[idx] = f2bf(1.f / (1.f + expf(-u)));
        } else if (EPI == EPI_VMIX) {
          float u = bias[col] + r;
          float sg = 1.f / (1.f + expf(-u));
          float v = bf2f(p1[idx]);
          float v0v = p2[idx];
          outB[idx] = f2bf(v + (v0v - v) * sg);
        }
      }
    }
  }
}

// ---------------------------------------------------------------- SIMT GEMM (skinny w1 paths)
__global__ __launch_bounds__(256)
void gemm_part_k(const u16* __restrict__ A, const float* __restrict__ W,
                 float* __restrict__ outF, int M, int N, int K, int kchunk,
                 int NP)
{
  __shared__ alignas(16) float As[16][68];
  __shared__ alignas(16) float Bs[16][68];
  const int m0 = blockIdx.x * 64;
  const int n0 = blockIdx.y * 64;
  const int kz = blockIdx.z;
  const int k0base = kz * kchunk;
  const int tid = threadIdx.x;
  const int tx = tid & 15, ty = tid >> 4;
  float acc[4][4] = {{0.f}};
  const int a_m = tid >> 2;
  const int a_k = (tid & 3) << 2;
  const int b_k = tid >> 4;
  const int b_n = (tid & 15) << 2;
  const int niters = kchunk >> 4;
  for (int it = 0; it < niters; ++it) {
    const int k0 = k0base + (it << 4);
    float4 av;
    {
      ushort4 u = *(const ushort4*)(A + (size_t)(m0 + a_m) * K + (k0 + a_k));
      av = make_float4(bf2f(u.x), bf2f(u.y), bf2f(u.z), bf2f(u.w));
    }
    float4 bv;
    {
      int gn = n0 + b_n;
      const float* wp = W + (size_t)(k0 + b_k) * N + gn;
      if (gn + 3 < N) {
        bv = *(const float4*)wp;
      } else {
        bv.x = (gn + 0 < N) ? wp[0] : 0.f;
        bv.y = (gn + 1 < N) ? wp[1] : 0.f;
        bv.z = (gn + 2 < N) ? wp[2] : 0.f;
        bv.w = (gn + 3 < N) ? wp[3] : 0.f;
      }
    }
    __syncthreads();
    As[a_k + 0][a_m] = av.x; As[a_k + 1][a_m] = av.y;
    As[a_k + 2][a_m] = av.z; As[a_k + 3][a_m] = av.w;
    Bs[b_k][b_n + 0] = bv.x; Bs[b_k][b_n + 1] = bv.y;
    Bs[b_k][b_n + 2] = bv.z; Bs[b_k][b_n + 3] = bv.w;
    __syncthreads();
    #pragma unroll
    for (int kk = 0; kk < 16; ++kk) {
      float4 a4 = *(const float4*)&As[kk][ty << 2];
      float4 b4 = *(const float4*)&Bs[kk][tx << 2];
      float ar[4] = {a4.x, a4.y, a4.z, a4.w};
      float br[4] = {b4.x, b4.y, b4.z, b4.w};
      #pragma unroll
      for (int i = 0; i < 4; ++i)
        #pragma unroll
        for (int j = 0; j < 4; ++j)
          acc[i][j] = fmaf(ar[i], br[j], acc[i][j]);
    }
  }
  #pragma unroll
  for (int i = 0; i < 4; ++i) {
    int gm = m0 + (ty << 2) + i;
    #pragma unroll
    for (int j = 0; j < 4; ++j) {
      int gn = n0 + (tx << 2) + j;
      if (gn >= N) continue;
      outF[((size_t)kz * M + gm) * NP + gn] = acc[i][j];
    }
  }
}

// ---------------------------------------------------------------- K-split reduce
__global__ __launch_bounds__(256)
void reduce_k(const float* __restrict__ part, u16* __restrict__ out,
              int M, int D, int NP, int nz, int act)
{
  int idx = blockIdx.x * 256 + threadIdx.x;
  if (idx >= M * D) return;
  int t = idx / D, n = idx - t * D;
  float s = 0.f;
  for (int z = 0; z < nz; ++z) s += part[((size_t)z * M + t) * NP + n];
  if (act == 1) s = tanhf(s);
  else if (act == 2) s = 1.f / (1.f + expf(-s));
  out[idx] = f2bf(s);
}

// ---------------------------------------------------------------- recurrence prep
// Per (b,t,h) wave (lane = j): from k, a, r, w_raw compute
//   kkn = normalize(k*kk_s);  ao=-kkn;  bo=kkn*a;  kf=k*(1+(a-1)*ka_s);
//   wd = exp(-exp(w_raw));    rw = wd*r;
//   scal[hidx] = (kr, br) = (sum_j kf*r, sum_j bo*r)  fp32
__global__ __launch_bounds__(256)
void prep_k(const u16* __restrict__ k_in, const u16* __restrict__ a_in,
            const u16* __restrict__ r_in, const u16* __restrict__ w_in,
            const float* __restrict__ kk_s, const float* __restrict__ ka_s,
            u16* __restrict__ ao_out, u16* __restrict__ bo_out,
            u16* __restrict__ k_out, u16* __restrict__ wd_out,
            u16* __restrict__ rw_out, float2* __restrict__ scal)
{
  int tid = threadIdx.x;
  int lane = tid & 63;
  int wv = tid >> 6;
  int hidx = blockIdx.x * 4 + wv;               // (b*T+t)*H + h
  int h = hidx & (HH - 1);
  int c = (h << 6) + lane;
  size_t base = ((size_t)hidx << 6) + lane;
  float k = bf2f(k_in[base]);
  float kk = k * kk_s[c];
  float ss = kk * kk;
  for (int off = 32; off; off >>= 1) ss += __shfl_xor(ss, off, 64);
  float kkn = kk / fmaxf(sqrtf(ss), 1e-12f);
  float a = bf2f(a_in[base]);
  float r = bf2f(r_in[base]);
  float kf = k * (1.f + (a - 1.f) * ka_s[c]);
  float wd = expf(-expf(bf2f(w_in[base])));
  float bo = kkn * a;
  ao_out[base] = f2bf(-kkn);
  bo_out[base] = f2bf(bo);
  k_out[base]  = f2bf(kf);
  wd_out[base] = f2bf(wd);
  rw_out[base] = f2bf(wd * r);
  float kr = kf * r, br = bo * r;
  kr += __shfl_xor(kr, 1, 64);  br += __shfl_xor(br, 1, 64);
  kr += __shfl_xor(kr, 2, 64);  br += __shfl_xor(br, 2, 64);
  kr += __shfl_xor(kr, 4, 64);  br += __shfl_xor(br, 4, 64);
  kr += __shfl_xor(kr, 8, 64);  br += __shfl_xor(br, 8, 64);
  kr += __shfl_xor(kr, 16, 64); br += __shfl_xor(br, 16, 64);
  kr += __shfl_xor(kr, 32, 64); br += __shfl_xor(br, 32, 64);
  if (lane == 0) scal[hidx] = make_float2(kr, br);
}

// ---------------------------------------------------------------- RWKV7 recurrence
// g=32 geometry: each row i gets a 32-lane group, 2 state elements per lane
// (j = sub*2, sub*2+1); one wave = 2 rows. 2048 waves = 2 waves/SIMD (2x TLP
// vs g=16) at 10 shfl/step/wave (5 butterfly levels x 2 reductions, masks
// 1..16 stay within each 32-lane group). 1-deep prefetch (R9 form; the
// 4-deep rotation of R10 regressed).
// y[i] = yw + sa*br + v[i]*kr on the pre-update state (round-8 identity).
__global__ __launch_bounds__(256)
void rec_k(const u16* __restrict__ rw, const u16* __restrict__ wd,
           const u16* __restrict__ kv, const u16* __restrict__ v,
           const u16* __restrict__ ao, const u16* __restrict__ bo,
           const float2* __restrict__ scal, u16* __restrict__ y)
{
  const int gw = blockIdx.x * 4 + (threadIdx.x >> 6);   // 0..2047
  const int lane = threadIdx.x & 63;
  const int sub = lane & 31;                    // j-subgroup (2 elems)
  const int grp = lane >> 5;                    // row within wave's 2-row block
  const int bh = gw >> 5;                       // 0..63
  const int rblk = gw & 31;
  const int i = rblk * 2 + grp;                 // value-dim row
  const int b = bh >> 5, h = bh & (HH - 1);
  const size_t base0 = ((size_t)b * TT) * CC + (h << 6);
  const size_t vecb = base0 + (sub << 1);       // j-vector base (us2)
  const size_t vb   = base0 + i;                // v, y
  const int sbase = b * TT * HH + h;            // + t*HH
  float s0 = 0.f, s1 = 0.f;
  us2 pwd = *(const us2*)(wd + vecb);
  us2 pk  = *(const us2*)(kv + vecb);
  us2 pao = *(const us2*)(ao + vecb);
  us2 pbo = *(const us2*)(bo + vecb);
  us2 prw = *(const us2*)(rw + vecb);
  float pv  = bf2f(v[vb]);
  float2 ps = scal[sbase];
  for (int t = 0; t < TT; ++t) {
    const float w0 = bf2f(pwd[0]), w1 = bf2f(pwd[1]);
    const float q0 = bf2f(pk[0]),  q1 = bf2f(pk[1]);
    const float a0 = bf2f(pao[0]), a1 = bf2f(pao[1]);
    const float c0 = bf2f(pbo[0]), c1 = bf2f(pbo[1]);
    const float e0 = bf2f(prw[0]), e1 = bf2f(prw[1]);
    const float cv = pv, ckr = ps.x, cbr = ps.y;
    if (t + 1 < TT) {
      const size_t nb = vecb + (size_t)(t + 1) * CC;
      pwd = *(const us2*)(wd + nb);
      pk  = *(const us2*)(kv + nb);
      pao = *(const us2*)(ao + nb);
      pbo = *(const us2*)(bo + nb);
      prw = *(const us2*)(rw + nb);
      pv  = bf2f(v[vb + (size_t)(t + 1) * CC]);
      ps  = scal[sbase + (t + 1) * HH];
    }
    float sa = fmaf(s1, a1, s0 * a0);
    float yw = fmaf(s1, e1, s0 * e0);
    sa += __shfl_xor(sa, 1, 64);  yw += __shfl_xor(yw, 1, 64);
    sa += __shfl_xor(sa, 2, 64);  yw += __shfl_xor(yw, 2, 64);
    sa += __shfl_xor(sa, 4, 64);  yw += __shfl_xor(yw, 4, 64);
    sa += __shfl_xor(sa, 8, 64);  yw += __shfl_xor(yw, 8, 64);
    sa += __shfl_xor(sa, 16, 64); yw += __shfl_xor(yw, 16, 64);
    s0 = fmaf(cv, q0, fmaf(sa, c0, s0 * w0));
    s1 = fmaf(cv, q1, fmaf(sa, c1, s1 * w1));
    float o = fmaf(cv, ckr, fmaf(sa, cbr, yw));
    if (sub == 0) y[vb + (size_t)t * CC] = f2bf(o);
  }
}

// ---------------------------------------------------------------- GroupNorm + bonus + gate
__global__ __launch_bounds__(256)
void gn_k(u16* __restrict__ y, const u16* __restrict__ r,
          const u16* __restrict__ k, const u16* __restrict__ v,
          const u16* __restrict__ g, const float* __restrict__ rk_s,
          const float* __restrict__ gn_w, const float* __restrict__ gn_b)
{
  int tid = threadIdx.x, lane = tid & 63, wv = tid >> 6;
  int hidx = blockIdx.x * 4 + wv;
  int h = hidx & (HH - 1);
  int c = (h << 6) + lane;
  size_t base = ((size_t)hidx << 6) + lane;
  float yv = bf2f(y[base]), rv = bf2f(r[base]), kv = bf2f(k[base]);
  float vv = bf2f(v[base]), gv = bf2f(g[base]);
  float bsum = rv * kv * rk_s[c];
  float s1 = yv, s2 = yv * yv;
  for (int off = 32; off; off >>= 1) {
    s1 += __shfl_xor(s1, off, 64);
    s2 += __shfl_xor(s2, off, 64);
    bsum += __shfl_xor(bsum, off, 64);
  }
  float mu = s1 * (1.f / 64.f);
  float var = s2 * (1.f / 64.f) - mu * mu;
  float rstd = rsqrtf(var + 0.00064f);
  float z = (yv - mu) * rstd * gn_w[c] + gn_b[c];
  y[base] = f2bf((z + bsum * vv) * gv);
}

// ---------------------------------------------------------------- helpers
__global__ __launch_bounds__(256)
void copy_v0(const float* __restrict__ v0, float* __restrict__ out) {
  int idx = blockIdx.x * 256 + threadIdx.x;
  ((float4*)out)[idx] = ((const float4*)v0)[idx];
}

__global__ __launch_bounds__(256)
void zero_out(float* __restrict__ out) {
  int idx = blockIdx.x * 256 + threadIdx.x;
  ((float4*)out)[idx] = make_float4(0.f, 0.f, 0.f, 0.f);
}

// ----------------------------------------------------------------
extern "C" void kernel_launch(void* const* d_in, const int* in_sizes, int n_in,
                              void* d_out, int out_size, void* d_ws, size_t ws_size,
                              hipStream_t stream) {
  (void)n_in; (void)out_size;
  const bool dictOrder = (in_sizes[9] == CC);
  int IX[28];
  if (dictOrder) {
    const int m[28] = {0,1,2,3,4,5,6,7, 8,13,14, 9,15,16, 10,17,18, 19,20,
                       11,12,21, 22,23,24,25, 26,27};
    for (int i = 0; i < 28; ++i) IX[i] = m[i];
  } else {
    for (int i = 0; i < 28; ++i) IX[i] = i;
  }
  const float* x     = (const float*)d_in[IX[0]];
  const float* v0    = (const float*)d_in[IX[1]];
  const float* xx_r  = (const float*)d_in[IX[2]];
  const float* xx_w  = (const float*)d_in[IX[3]];
  const float* xx_k  = (const float*)d_in[IX[4]];
  const float* xx_v  = (const float*)d_in[IX[5]];
  const float* xx_a  = (const float*)d_in[IX[6]];
  const float* xx_g  = (const float*)d_in[IX[7]];
  const float* ww_b  = (const float*)d_in[IX[8]];
  const float* ww_w1 = (const float*)d_in[IX[9]];
  const float* ww_w2 = (const float*)d_in[IX[10]];
  const float* aa_b  = (const float*)d_in[IX[11]];
  const float* aa_w1 = (const float*)d_in[IX[12]];
  const float* aa_w2 = (const float*)d_in[IX[13]];
  const float* vv_b  = (const float*)d_in[IX[14]];
  const float* vv_w1 = (const float*)d_in[IX[15]];
  const float* vv_w2 = (const float*)d_in[IX[16]];
  const float* gg_w1 = (const float*)d_in[IX[17]];
  const float* gg_w2 = (const float*)d_in[IX[18]];
  const float* kk_s  = (const float*)d_in[IX[19]];
  const float* ka_s  = (const float*)d_in[IX[20]];
  const float* rk_s  = (const float*)d_in[IX[21]];
  const float* W_r   = (const float*)d_in[IX[22]];
  const float* W_k   = (const float*)d_in[IX[23]];
  const float* W_v   = (const float*)d_in[IX[24]];
  const float* W_o   = (const float*)d_in[IX[25]];
  const float* gn_w  = (const float*)d_in[IX[26]];
  const float* gn_b  = (const float*)d_in[IX[27]];

  const size_t NBTC = (size_t)BT * CC;
  dim3 blk(256);
  const int grid4f = (int)(NBTC / 4 / 256);

  const size_t WS_NEED = 7 * NBTC * sizeof(u16);
  float* outF = (float*)d_out;
  if (ws_size < WS_NEED || d_ws == nullptr) {
    zero_out<<<grid4f, blk, 0, stream>>>(outF);
    copy_v0<<<grid4f, blk, 0, stream>>>(v0, outF + NBTC);
    return;
  }

  // Regions: R0=h1/r  R1=Wt(early)/k  R2=v  R3=partY/Wt/ao/h2
  // R4=a/bo/g  R5=w_raw/wd -> partG/Wt(g,o)  R6=mix staging/rw.
  // y (bf16) in d_out v0-slot front half; kr/br float2 in its back half.
  u16* W16   = (u16*)d_ws;
  u16* R0 = W16 + 0 * NBTC;
  u16* R1 = W16 + 1 * NBTC;
  u16* R2 = W16 + 2 * NBTC;
  u16* R3 = W16 + 3 * NBTC;
  u16* R4 = W16 + 4 * NBTC;
  u16* R5 = W16 + 5 * NBTC;
  u16* R6 = W16 + 6 * NBTC;
  float* partY = (float*)R3;
  float* partG = (float*)R5;
  u16* ws_y = (u16*)(outF + NBTC);          // bf16 y: front half of v0 slot
  float2* scal = (float2*)(ws_y + NBTC);    // kr/br in back half

  const int gridMix = (BT * CC) / 256;
  dim3 gM(BT / 128, 2048 / 128);            // (16, 16)

  // ---- w path
  mix_k<<<gridMix, blk, 0, stream>>>(x, xx_w, R6);
  gemm_part_k<<<dim3(32, 2, 8), blk, 0, stream>>>(R6, ww_w1, partY,
      BT, 96, 2048, 256, 128);
  reduce_k<<<(BT * 96 + 255) / 256, blk, 0, stream>>>(partY, R0, BT, 96, 128, 8, 1);
  wt_k<<<dim3(3, 64), blk, 0, stream>>>(ww_w2, R1, 96, 2048);
  mgemm_k<EPI_BIAS_SP><<<gM, blk, 0, stream>>>(R0, R1, nullptr, R5,
      BT, 2048, 96, ww_b, nullptr, nullptr);

  // ---- a path
  mix_k<<<gridMix, blk, 0, stream>>>(x, xx_a, R6);
  gemm_part_k<<<dim3(32, 2, 8), blk, 0, stream>>>(R6, aa_w1, partY,
      BT, 96, 2048, 256, 128);
  reduce_k<<<(BT * 96 + 255) / 256, blk, 0, stream>>>(partY, R0, BT, 96, 128, 8, 0);
  wt_k<<<dim3(3, 64), blk, 0, stream>>>(aa_w2, R1, 96, 2048);
  mgemm_k<EPI_BIAS_SIG><<<gM, blk, 0, stream>>>(R0, R1, nullptr, R4,
      BT, 2048, 96, aa_b, nullptr, nullptr);

  // ---- v path
  mix_k<<<gridMix, blk, 0, stream>>>(x, xx_v, R6);
  wt_k<<<dim3(64, 64), blk, 0, stream>>>(W_v, R1, 2048, 2048);
  mgemm_k<EPI_BF><<<gM, blk, 0, stream>>>(R6, R1, nullptr, R2,
      BT, 2048, 2048, nullptr, nullptr, nullptr);
  gemm_part_k<<<dim3(32, 1, 8), blk, 0, stream>>>(R6, vv_w1, partY,
      BT, 64, 2048, 256, 64);
  reduce_k<<<(BT * 64 + 255) / 256, blk, 0, stream>>>(partY, R0, BT, 64, 64, 8, 0);
  wt_k<<<dim3(2, 64), blk, 0, stream>>>(vv_w2, R1, 64, 2048);
  mgemm_k<EPI_VMIX><<<gM, blk, 0, stream>>>(R0, R1, nullptr, R2,
      BT, 2048, 64, vv_b, R2, v0);

  // ---- k path
  mix_k<<<gridMix, blk, 0, stream>>>(x, xx_k, R6);
  wt_k<<<dim3(64, 64), blk, 0, stream>>>(W_k, R3, 2048, 2048);
  mgemm_k<EPI_BF><<<gM, blk, 0, stream>>>(R6, R3, nullptr, R1,
      BT, 2048, 2048, nullptr, nullptr, nullptr);

  // ---- r path
  mix_k<<<gridMix, blk, 0, stream>>>(x, xx_r, R6);
  wt_k<<<dim3(64, 64), blk, 0, stream>>>(W_r, R3, 2048, 2048);
  mgemm_k<EPI_BF><<<gM, blk, 0, stream>>>(R6, R3, nullptr, R0,
      BT, 2048, 2048, nullptr, nullptr, nullptr);

  // ---- recurrence prep: k(R1),a(R4),r(R0),w_raw(R5) ->
  //      ao(R3), bo(R4), kf(R1), wd(R5), rw(R6), scal
  prep_k<<<BT * HH / 4, blk, 0, stream>>>(R1, R4, R0, R5, kk_s, ka_s,
                                          R3, R4, R1, R5, R6, scal);

  // ---- recurrence (g=32, 2 waves/SIMD): rw=R6 wd=R5 k=R1 v=R2 ao=R3 bo=R4
  rec_k<<<512, blk, 0, stream>>>(R6, R5, R1, R2, R3, R4, scal, ws_y);

  // ---- g path (R5, R3, R4, R6 dead after rec)
  mix_k<<<gridMix, blk, 0, stream>>>(x, xx_g, R6);
  gemm_part_k<<<dim3(32, 4, 2), blk, 0, stream>>>(R6, gg_w1, partG,
      BT, 256, 2048, 1024, 256);
  reduce_k<<<(BT * 256 + 255) / 256, blk, 0, stream>>>(partG, R3, BT, 256, 256, 2, 2);
  wt_k<<<dim3(8, 64), blk, 0, stream>>>(gg_w2, R5, 256, 2048);
  mgemm_k<EPI_BF><<<gM, blk, 0, stream>>>(R3, R5, nullptr, R4,
      BT, 2048, 256, nullptr, nullptr, nullptr);

  // ---- groupnorm + bonus + gate (in place on y)
  gn_k<<<BT * HH / 4, blk, 0, stream>>>(ws_y, R0, R1, R2, R4,
                                        rk_s, gn_w, gn_b);

  // ---- final projection y @ W_o -> fp32 output 0
  wt_k<<<dim3(64, 64), blk, 0, stream>>>(W_o, R5, 2048, 2048);
  mgemm_k<EPI_F32><<<gM, blk, 0, stream>>>(ws_y, R5, outF, nullptr,
      BT, 2048, 2048, nullptr, nullptr, nullptr);

  // ---- v0 passthrough (overwrites y scratch + scal, last)
  copy_v0<<<grid4f, blk, 0, stream>>>(v0, outF + NBTC);
}

// Round 12
// 866.325 us; speedup vs baseline: 1.3068x; 1.1242x over previous
//
#include <hip/hip_runtime.h>
#include <hip/hip_bf16.h>
#include <math.h>

typedef unsigned short u16;
typedef __attribute__((ext_vector_type(4))) unsigned short us4;
typedef __attribute__((ext_vector_type(8))) unsigned short us8;
typedef __attribute__((ext_vector_type(8))) short s8v;   // mfma bf16 operand (4 VGPRs)
typedef __attribute__((ext_vector_type(4))) float f4v;   // mfma accum

#define BB 2
#define TT 1024
#define CC 2048
#define HH 32
#define BT (BB*TT)

// Inputs/outputs fp32. ws intermediates bf16: 7 regions x NBTC u16.
// Weights cvt-transposed to bf16 [N][K] just-in-time into dead regions for
// the MFMA GEMMs. Recurrence scalars (kr,br per (b,t,h); pair scalars
// cba,ckb,crb,crk per (b,tp,h)) live in the back half of d_out's v0 slot.

__device__ __forceinline__ float bf2f(u16 u) {
  return __uint_as_float(((unsigned int)u) << 16);
}
__device__ __forceinline__ u16 f2bf(float f) {
  unsigned int x = __float_as_uint(f);
  x += 0x7fffu + ((x >> 16) & 1u);
  return (u16)(x >> 16);
}

// ---------------------------------------------------------------- mix kernel
__global__ __launch_bounds__(256)
void mix_k(const float* __restrict__ x, const float* __restrict__ s,
           u16* __restrict__ out) {
  int idx = blockIdx.x * 256 + threadIdx.x;       // over BT*C
  int c = idx & (CC - 1);
  int t = (idx >> 11) & (TT - 1);
  float xv = x[idx];
  float xp = (t == 0) ? 0.f : x[idx - CC];
  out[idx] = f2bf(xv + (xp - xv) * s[c]);
}

// ---------------------------------------------------------------- weight cvt-transpose
// W fp32 [K][N] -> Wt bf16 [N][K]. 32x32 tiles, 256 threads.
__global__ __launch_bounds__(256)
void wt_k(const float* __restrict__ W, u16* __restrict__ Wt, int K, int N) {
  __shared__ u16 tile[32][36];
  const int k0 = blockIdx.x * 32, n0 = blockIdx.y * 32;
  const int tid = threadIdx.x;
  const int r = tid >> 3, c4 = (tid & 7) << 2;
  float4 v = *(const float4*)(W + (size_t)(k0 + r) * N + n0 + c4);
  tile[r][c4 + 0] = f2bf(v.x); tile[r][c4 + 1] = f2bf(v.y);
  tile[r][c4 + 2] = f2bf(v.z); tile[r][c4 + 3] = f2bf(v.w);
  __syncthreads();
  ushort4 o;
  o.x = tile[c4 + 0][r]; o.y = tile[c4 + 1][r];
  o.z = tile[c4 + 2][r]; o.w = tile[c4 + 3][r];
  *(ushort4*)(Wt + (size_t)(n0 + r) * K + k0 + c4) = o;
}

// ---------------------------------------------------------------- MFMA GEMM
// C[M,N] = A[M,K](bf16, pitch K) * B(given as Bt[N][K] bf16), fp32 accum.
// Block tile 128x128, BK=32, 4 waves (2x2), wave tile 64x64 = 4x4 frags.
enum { EPI_BF = 0, EPI_F32 = 1, EPI_BIAS_SP = 2, EPI_BIAS_SIG = 3,
       EPI_VMIX = 4 };

template<int EPI>
__global__ __launch_bounds__(256)
void mgemm_k(const u16* __restrict__ A, const u16* __restrict__ Bt,
             float* __restrict__ outF, u16* __restrict__ outB,
             int M, int N, int K,
             const float* __restrict__ bias, const u16* __restrict__ p1,
             const float* __restrict__ p2)
{
  __shared__ alignas(16) u16 As[128][40];   // 32 k + 8 pad (80 B row stride)
  __shared__ alignas(16) u16 Bs[128][40];
  const int m0 = blockIdx.x * 128;
  const int n0 = blockIdx.y * 128;
  const int tid = threadIdx.x;
  const int lane = tid & 63;
  const int wid = tid >> 6;
  const int wr = wid >> 1, wc = wid & 1;        // wave quadrant (2x2)
  const int srow = tid >> 1;                    // staging row (0..127)
  const int scol = (tid & 1) << 4;              // staging k-col (0 or 16)
  f4v acc[4][4];
  #pragma unroll
  for (int i = 0; i < 4; ++i)
    #pragma unroll
    for (int j = 0; j < 4; ++j) acc[i][j] = f4v{0.f, 0.f, 0.f, 0.f};

  const int l15 = lane & 15;
  const int lk = (lane >> 4) << 3;              // k offset within BK (0,8,16,24)
  const int nkt = K >> 5;
  for (int kt = 0; kt < nkt; ++kt) {
    const int k0 = kt << 5;
    const u16* ap = A  + (size_t)(m0 + srow) * K + k0 + scol;
    const u16* bp = Bt + (size_t)(n0 + srow) * K + k0 + scol;
    us8 a0 = *(const us8*)(ap);
    us8 a1 = *(const us8*)(ap + 8);
    us8 b0 = *(const us8*)(bp);
    us8 b1 = *(const us8*)(bp + 8);
    __syncthreads();                            // prev compute done
    *(us8*)&As[srow][scol]     = a0;
    *(us8*)&As[srow][scol + 8] = a1;
    *(us8*)&Bs[srow][scol]     = b0;
    *(us8*)&Bs[srow][scol + 8] = b1;
    __syncthreads();
    s8v af[4], bfr[4];
    #pragma unroll
    for (int i = 0; i < 4; ++i)
      af[i] = *(const s8v*)&As[wr * 64 + i * 16 + l15][lk];
    #pragma unroll
    for (int j = 0; j < 4; ++j)
      bfr[j] = *(const s8v*)&Bs[wc * 64 + j * 16 + l15][lk];
    #pragma unroll
    for (int i = 0; i < 4; ++i)
      #pragma unroll
      for (int j = 0; j < 4; ++j)
        acc[i][j] = __builtin_amdgcn_mfma_f32_16x16x32_bf16(af[i], bfr[j],
                                                            acc[i][j], 0, 0, 0);
  }
  // C/D layout: col = lane&15, row = (lane>>4)*4 + q  (m89-verified)
  const int rbase = m0 + wr * 64 + ((lane >> 4) << 2);
  const int cbase = n0 + wc * 64 + l15;
  #pragma unroll
  for (int i = 0; i < 4; ++i) {
    #pragma unroll
    for (int j = 0; j < 4; ++j) {
      f4v c = acc[i][j];
      const int col = cbase + j * 16;
      #pragma unroll
      for (int q = 0; q < 4; ++q) {
        const int row = rbase + i * 16 + q;
        const size_t idx = (size_t)row * N + col;
        const float r = c[q];
        if (EPI == EPI_BF) {
          outB[idx] = f2bf(r);
        } else if (EPI == EPI_F32) {
          outF[idx] = r;
        } else if (EPI == EPI_BIAS_SP) {
          float u = bias[col] + r;
          float z = -u;
          float sp = fmaxf(z, 0.f) + log1pf(expf(-fabsf(z)));
          outB[idx] = f2bf(-sp - 0.5f);
        } else if (EPI == EPI_BIAS_SIG) {
          float u = bias[col] + r;
          outB[idx] = f2bf(1.f / (1.f + expf(-u)));
        } else if (EPI == EPI_VMIX) {
          float u = bias[col] + r;
          float sg = 1.f / (1.f + expf(-u));
          float v = bf2f(p1[idx]);
          float v0v = p2[idx];
          outB[idx] = f2bf(v + (v0v - v) * sg);
        }
      }
    }
  }
}

// ---------------------------------------------------------------- SIMT GEMM (skinny w1 paths)
__global__ __launch_bounds__(256)
void gemm_part_k(const u16* __restrict__ A, const float* __restrict__ W,
                 float* __restrict__ outF, int M, int N, int K, int kchunk,
                 int NP)
{
  __shared__ alignas(16) float As[16][68];
  __shared__ alignas(16) float Bs[16][68];
  const int m0 = blockIdx.x * 64;
  const int n0 = blockIdx.y * 64;
  const int kz = blockIdx.z;
  const int k0base = kz * kchunk;
  const int tid = threadIdx.x;
  const int tx = tid & 15, ty = tid >> 4;
  float acc[4][4] = {{0.f}};
  const int a_m = tid >> 2;
  const int a_k = (tid & 3) << 2;
  const int b_k = tid >> 4;
  const int b_n = (tid & 15) << 2;
  const int niters = kchunk >> 4;
  for (int it = 0; it < niters; ++it) {
    const int k0 = k0base + (it << 4);
    float4 av;
    {
      ushort4 u = *(const ushort4*)(A + (size_t)(m0 + a_m) * K + (k0 + a_k));
      av = make_float4(bf2f(u.x), bf2f(u.y), bf2f(u.z), bf2f(u.w));
    }
    float4 bv;
    {
      int gn = n0 + b_n;
      const float* wp = W + (size_t)(k0 + b_k) * N + gn;
      if (gn + 3 < N) {
        bv = *(const float4*)wp;
      } else {
        bv.x = (gn + 0 < N) ? wp[0] : 0.f;
        bv.y = (gn + 1 < N) ? wp[1] : 0.f;
        bv.z = (gn + 2 < N) ? wp[2] : 0.f;
        bv.w = (gn + 3 < N) ? wp[3] : 0.f;
      }
    }
    __syncthreads();
    As[a_k + 0][a_m] = av.x; As[a_k + 1][a_m] = av.y;
    As[a_k + 2][a_m] = av.z; As[a_k + 3][a_m] = av.w;
    Bs[b_k][b_n + 0] = bv.x; Bs[b_k][b_n + 1] = bv.y;
    Bs[b_k][b_n + 2] = bv.z; Bs[b_k][b_n + 3] = bv.w;
    __syncthreads();
    #pragma unroll
    for (int kk = 0; kk < 16; ++kk) {
      float4 a4 = *(const float4*)&As[kk][ty << 2];
      float4 b4 = *(const float4*)&Bs[kk][tx << 2];
      float ar[4] = {a4.x, a4.y, a4.z, a4.w};
      float br[4] = {b4.x, b4.y, b4.z, b4.w};
      #pragma unroll
      for (int i = 0; i < 4; ++i)
        #pragma unroll
        for (int j = 0; j < 4; ++j)
          acc[i][j] = fmaf(ar[i], br[j], acc[i][j]);
    }
  }
  #pragma unroll
  for (int i = 0; i < 4; ++i) {
    int gm = m0 + (ty << 2) + i;
    #pragma unroll
    for (int j = 0; j < 4; ++j) {
      int gn = n0 + (tx << 2) + j;
      if (gn >= N) continue;
      outF[((size_t)kz * M + gm) * NP + gn] = acc[i][j];
    }
  }
}

// ---------------------------------------------------------------- K-split reduce
__global__ __launch_bounds__(256)
void reduce_k(const float* __restrict__ part, u16* __restrict__ out,
              int M, int D, int NP, int nz, int act)
{
  int idx = blockIdx.x * 256 + threadIdx.x;
  if (idx >= M * D) return;
  int t = idx / D, n = idx - t * D;
  float s = 0.f;
  for (int z = 0; z < nz; ++z) s += part[((size_t)z * M + t) * NP + n];
  if (act == 1) s = tanhf(s);
  else if (act == 2) s = 1.f / (1.f + expf(-s));
  out[idx] = f2bf(s);
}

// ---------------------------------------------------------------- recurrence prep
// Per (b,t,h) wave (lane = j): from k, a, r, w_raw compute
//   kkn = normalize(k*kk_s);  ao=-kkn;  bo=kkn*a;  kf=k*(1+(a-1)*ka_s);
//   wd = exp(-exp(w_raw));    rw = wd*r;
//   scal[hidx] = (kr, br) = (sum_j kf*r, sum_j bo*r)  fp32
__global__ __launch_bounds__(256)
void prep_k(const u16* __restrict__ k_in, const u16* __restrict__ a_in,
            const u16* __restrict__ r_in, const u16* __restrict__ w_in,
            const float* __restrict__ kk_s, const float* __restrict__ ka_s,
            u16* __restrict__ ao_out, u16* __restrict__ bo_out,
            u16* __restrict__ k_out, u16* __restrict__ wd_out,
            u16* __restrict__ rw_out, float2* __restrict__ scal)
{
  int tid = threadIdx.x;
  int lane = tid & 63;
  int wv = tid >> 6;
  int hidx = blockIdx.x * 4 + wv;               // (b*T+t)*H + h
  int h = hidx & (HH - 1);
  int c = (h << 6) + lane;
  size_t base = ((size_t)hidx << 6) + lane;
  float k = bf2f(k_in[base]);
  float kk = k * kk_s[c];
  float ss = kk * kk;
  for (int off = 32; off; off >>= 1) ss += __shfl_xor(ss, off, 64);
  float kkn = kk / fmaxf(sqrtf(ss), 1e-12f);
  float a = bf2f(a_in[base]);
  float r = bf2f(r_in[base]);
  float kf = k * (1.f + (a - 1.f) * ka_s[c]);
  float wd = expf(-expf(bf2f(w_in[base])));
  float bo = kkn * a;
  ao_out[base] = f2bf(-kkn);
  bo_out[base] = f2bf(bo);
  k_out[base]  = f2bf(kf);
  wd_out[base] = f2bf(wd);
  rw_out[base] = f2bf(wd * r);
  float kr = kf * r, br = bo * r;
  kr += __shfl_xor(kr, 1, 64);  br += __shfl_xor(br, 1, 64);
  kr += __shfl_xor(kr, 2, 64);  br += __shfl_xor(br, 2, 64);
  kr += __shfl_xor(kr, 4, 64);  br += __shfl_xor(br, 4, 64);
  kr += __shfl_xor(kr, 8, 64);  br += __shfl_xor(br, 8, 64);
  kr += __shfl_xor(kr, 16, 64); br += __shfl_xor(br, 16, 64);
  kr += __shfl_xor(kr, 32, 64); br += __shfl_xor(br, 32, 64);
  if (lane == 0) scal[hidx] = make_float2(kr, br);
}

// ---------------------------------------------------------------- pair prep
// Two-step compounding: for each timestep pair (t=2tp, 2tp+1) build
//   w12 = wd1*wd2      -> wd[even]      (replaces wd1)
//   kw1 = kf1*wd2      -> wd[odd]       (replaces wd2)
//   wa2 = wd1*ao2      -> ao[odd]       (ao1 stays at ao[even])
//   bw1 = bo1*wd2      -> bo[even]      (bo2 stays at bo[odd])
//   wrw2 = wd1*rw2     -> rw[odd]       (rw1 stays at rw[even])
//   scal4 = (cba=bo1.ao2, ckb=kf1.ao2, crb=bo1.rw2, crk=kf1.rw2)
// All reads/writes of a given element are same-lane, so in-place is safe.
__global__ __launch_bounds__(256)
void prep2_k(u16* __restrict__ wd, u16* __restrict__ ao,
             u16* __restrict__ bo, u16* __restrict__ rw,
             const u16* __restrict__ kf, float4* __restrict__ scal4)
{
  int tid = threadIdx.x;
  int lane = tid & 63;
  int wv = tid >> 6;
  int hpidx = blockIdx.x * 4 + wv;              // over (b, tp, h), h fastest
  int h = hpidx & (HH - 1);
  int btp = hpidx >> 5;                         // 0 .. BB*TT/2-1
  int tp = btp & (TT / 2 - 1);
  int b = btp >> 9;                             // TT/2 = 512
  size_t be = ((size_t)(b * TT + 2 * tp)) * CC + (h << 6) + lane;
  size_t bodd = be + CC;
  float wd1 = bf2f(wd[be]),  wd2 = bf2f(wd[bodd]);
  float ao2 = bf2f(ao[bodd]), rw2 = bf2f(rw[bodd]);
  float bo1 = bf2f(bo[be]),  k1  = bf2f(kf[be]);
  float cba = bo1 * ao2, ckb = k1 * ao2, crb = bo1 * rw2, crk = k1 * rw2;
  #pragma unroll
  for (int off = 32; off; off >>= 1) {
    cba += __shfl_xor(cba, off, 64);
    ckb += __shfl_xor(ckb, off, 64);
    crb += __shfl_xor(crb, off, 64);
    crk += __shfl_xor(crk, off, 64);
  }
  wd[be]   = f2bf(wd1 * wd2);
  wd[bodd] = f2bf(k1 * wd2);
  ao[bodd] = f2bf(wd1 * ao2);
  bo[be]   = f2bf(bo1 * wd2);
  rw[bodd] = f2bf(wd1 * rw2);
  if (lane == 0) scal4[hpidx] = make_float4(cba, ckb, crb, crk);
}

// ---------------------------------------------------------------- RWKV7 recurrence
// g=16 geometry + 2-step compounding: one iteration advances TWO timesteps
// with a SINGLE 4-level butterfly round (4 interleaved reductions u1,u2,q1,q2
// on the same pre-pair state). Identities:
//   u1=S.ao1  u2=S.wa2  q1=S.rw1  q2=S.wrw2
//   sac = u2 + cba*u1 + ckb*v1
//   y1  = q1 + br1*u1 + kr1*v1
//   y2  = q2 + crb*u1 + crk*v1 + br2*sac + kr2*v2
//   S'  = S*w12 + u1*bw1 + sac*bo2 + v1*kw1 + v2*k2
__global__ __launch_bounds__(256)
void rec_k(const u16* __restrict__ rw, const u16* __restrict__ wd,
           const u16* __restrict__ kv, const u16* __restrict__ v,
           const u16* __restrict__ ao, const u16* __restrict__ bo,
           const float2* __restrict__ scal, const float4* __restrict__ scal4,
           u16* __restrict__ y)
{
  const int gw = blockIdx.x * 4 + (threadIdx.x >> 6);   // 0..1023
  const int lane = threadIdx.x & 63;
  const int sub = lane & 15;                    // j-subgroup within row
  const int grp = lane >> 4;                    // row within wave's 4-row block
  const int bh = gw >> 4;                       // 0..63
  const int rblk = gw & 15;
  const int i = rblk * 4 + grp;                 // value-dim row
  const int b = bh >> 5, h = bh & (HH - 1);
  const size_t base0 = ((size_t)b * TT) * CC + (h << 6);
  const size_t vecb = base0 + (sub << 2);       // j-vector base (us4)
  const size_t vb   = base0 + i;                // v, y
  const int sbase = b * TT * HH + h;            // + t*HH
  const int pbase = b * (TT / 2) * HH + h;      // + tp*HH
  float s0 = 0.f, s1 = 0.f, s2 = 0.f, s3 = 0.f;

  us4 W12, KW1, AO1, WA2, BW1, BO2, RW1, WR2, K2;
  float V1, V2; float2 SE, SO; float4 S4;
#define PLOAD(TP) do {                                                  \
    const size_t be_ = vecb + (size_t)(2 * (TP)) * CC;                  \
    const size_t bo_ = be_ + CC;                                        \
    W12 = *(const us4*)(wd + be_);  KW1 = *(const us4*)(wd + bo_);      \
    AO1 = *(const us4*)(ao + be_);  WA2 = *(const us4*)(ao + bo_);      \
    BW1 = *(const us4*)(bo + be_);  BO2 = *(const us4*)(bo + bo_);      \
    RW1 = *(const us4*)(rw + be_);  WR2 = *(const us4*)(rw + bo_);      \
    K2  = *(const us4*)(kv + bo_);                                      \
    V1 = bf2f(v[vb + (size_t)(2 * (TP)) * CC]);                         \
    V2 = bf2f(v[vb + (size_t)(2 * (TP) + 1) * CC]);                     \
    SE = scal[sbase + (2 * (TP)) * HH];                                 \
    SO = scal[sbase + (2 * (TP) + 1) * HH];                             \
    S4 = scal4[pbase + (TP) * HH];                                      \
  } while (0)

  PLOAD(0);
  for (int tp = 0; tp < TT / 2; ++tp) {
    const float w0 = bf2f(W12[0]), w1 = bf2f(W12[1]),
                w2 = bf2f(W12[2]), w3 = bf2f(W12[3]);
    const float kw0 = bf2f(KW1[0]), kw1_ = bf2f(KW1[1]),
                kw2 = bf2f(KW1[2]), kw3 = bf2f(KW1[3]);
    const float a0 = bf2f(AO1[0]), a1 = bf2f(AO1[1]),
                a2 = bf2f(AO1[2]), a3 = bf2f(AO1[3]);
    const float x0 = bf2f(WA2[0]), x1 = bf2f(WA2[1]),
                x2 = bf2f(WA2[2]), x3 = bf2f(WA2[3]);
    const float bw0 = bf2f(BW1[0]), bw1_ = bf2f(BW1[1]),
                bw2 = bf2f(BW1[2]), bw3 = bf2f(BW1[3]);
    const float b0 = bf2f(BO2[0]), b1 = bf2f(BO2[1]),
                b2 = bf2f(BO2[2]), b3 = bf2f(BO2[3]);
    const float e0 = bf2f(RW1[0]), e1 = bf2f(RW1[1]),
                e2 = bf2f(RW1[2]), e3 = bf2f(RW1[3]);
    const float f0 = bf2f(WR2[0]), f1 = bf2f(WR2[1]),
                f2 = bf2f(WR2[2]), f3 = bf2f(WR2[3]);
    const float k0 = bf2f(K2[0]), k1 = bf2f(K2[1]),
                k2 = bf2f(K2[2]), k3 = bf2f(K2[3]);
    const float v1c = V1, v2c = V2;
    const float kr1 = SE.x, br1 = SE.y, kr2 = SO.x, br2 = SO.y;
    const float cba = S4.x, ckb = S4.y, crb = S4.z, crk = S4.w;
    if (tp + 1 < TT / 2) PLOAD(tp + 1);
    float u1 = fmaf(s3, a3, fmaf(s2, a2, fmaf(s1, a1, s0 * a0)));
    float u2 = fmaf(s3, x3, fmaf(s2, x2, fmaf(s1, x1, s0 * x0)));
    float q1 = fmaf(s3, e3, fmaf(s2, e2, fmaf(s1, e1, s0 * e0)));
    float q2 = fmaf(s3, f3, fmaf(s2, f2, fmaf(s1, f1, s0 * f0)));
    u1 += __shfl_xor(u1, 1, 64);  u2 += __shfl_xor(u2, 1, 64);
    q1 += __shfl_xor(q1, 1, 64);  q2 += __shfl_xor(q2, 1, 64);
    u1 += __shfl_xor(u1, 2, 64);  u2 += __shfl_xor(u2, 2, 64);
    q1 += __shfl_xor(q1, 2, 64);  q2 += __shfl_xor(q2, 2, 64);
    u1 += __shfl_xor(u1, 4, 64);  u2 += __shfl_xor(u2, 4, 64);
    q1 += __shfl_xor(q1, 4, 64);  q2 += __shfl_xor(q2, 4, 64);
    u1 += __shfl_xor(u1, 8, 64);  u2 += __shfl_xor(u2, 8, 64);
    q1 += __shfl_xor(q1, 8, 64);  q2 += __shfl_xor(q2, 8, 64);
    const float sac = fmaf(ckb, v1c, fmaf(cba, u1, u2));
    const float y1 = fmaf(br1, u1, fmaf(kr1, v1c, q1));
    const float y2 = fmaf(br2, sac, fmaf(kr2, v2c,
                       fmaf(crb, u1, fmaf(crk, v1c, q2))));
    s0 = fmaf(v2c, k0, fmaf(v1c, kw0, fmaf(sac, b0, fmaf(u1, bw0, s0 * w0))));
    s1 = fmaf(v2c, k1, fmaf(v1c, kw1_, fmaf(sac, b1, fmaf(u1, bw1_, s1 * w1))));
    s2 = fmaf(v2c, k2, fmaf(v1c, kw2, fmaf(sac, b2, fmaf(u1, bw2, s2 * w2))));
    s3 = fmaf(v2c, k3, fmaf(v1c, kw3, fmaf(sac, b3, fmaf(u1, bw3, s3 * w3))));
    if (sub == 0) {
      y[vb + (size_t)(2 * tp) * CC] = f2bf(y1);
      y[vb + (size_t)(2 * tp + 1) * CC] = f2bf(y2);
    }
  }
#undef PLOAD
}

// ---------------------------------------------------------------- GroupNorm + bonus + gate
__global__ __launch_bounds__(256)
void gn_k(u16* __restrict__ y, const u16* __restrict__ r,
          const u16* __restrict__ k, const u16* __restrict__ v,
          const u16* __restrict__ g, const float* __restrict__ rk_s,
          const float* __restrict__ gn_w, const float* __restrict__ gn_b)
{
  int tid = threadIdx.x, lane = tid & 63, wv = tid >> 6;
  int hidx = blockIdx.x * 4 + wv;
  int h = hidx & (HH - 1);
  int c = (h << 6) + lane;
  size_t base = ((size_t)hidx << 6) + lane;
  float yv = bf2f(y[base]), rv = bf2f(r[base]), kv = bf2f(k[base]);
  float vv = bf2f(v[base]), gv = bf2f(g[base]);
  float bsum = rv * kv * rk_s[c];
  float s1 = yv, s2 = yv * yv;
  for (int off = 32; off; off >>= 1) {
    s1 += __shfl_xor(s1, off, 64);
    s2 += __shfl_xor(s2, off, 64);
    bsum += __shfl_xor(bsum, off, 64);
  }
  float mu = s1 * (1.f / 64.f);
  float var = s2 * (1.f / 64.f) - mu * mu;
  float rstd = rsqrtf(var + 0.00064f);
  float z = (yv - mu) * rstd * gn_w[c] + gn_b[c];
  y[base] = f2bf((z + bsum * vv) * gv);
}

// ---------------------------------------------------------------- helpers
__global__ __launch_bounds__(256)
void copy_v0(const float* __restrict__ v0, float* __restrict__ out) {
  int idx = blockIdx.x * 256 + threadIdx.x;
  ((float4*)out)[idx] = ((const float4*)v0)[idx];
}

__global__ __launch_bounds__(256)
void zero_out(float* __restrict__ out) {
  int idx = blockIdx.x * 256 + threadIdx.x;
  ((float4*)out)[idx] = make_float4(0.f, 0.f, 0.f, 0.f);
}

// ----------------------------------------------------------------
extern "C" void kernel_launch(void* const* d_in, const int* in_sizes, int n_in,
                              void* d_out, int out_size, void* d_ws, size_t ws_size,
                              hipStream_t stream) {
  (void)n_in; (void)out_size;
  const bool dictOrder = (in_sizes[9] == CC);
  int IX[28];
  if (dictOrder) {
    const int m[28] = {0,1,2,3,4,5,6,7, 8,13,14, 9,15,16, 10,17,18, 19,20,
                       11,12,21, 22,23,24,25, 26,27};
    for (int i = 0; i < 28; ++i) IX[i] = m[i];
  } else {
    for (int i = 0; i < 28; ++i) IX[i] = i;
  }
  const float* x     = (const float*)d_in[IX[0]];
  const float* v0    = (const float*)d_in[IX[1]];
  const float* xx_r  = (const float*)d_in[IX[2]];
  const float* xx_w  = (const float*)d_in[IX[3]];
  const float* xx_k  = (const float*)d_in[IX[4]];
  const float* xx_v  = (const float*)d_in[IX[5]];
  const float* xx_a  = (const float*)d_in[IX[6]];
  const float* xx_g  = (const float*)d_in[IX[7]];
  const float* ww_b  = (const float*)d_in[IX[8]];
  const float* ww_w1 = (const float*)d_in[IX[9]];
  const float* ww_w2 = (const float*)d_in[IX[10]];
  const float* aa_b  = (const float*)d_in[IX[11]];
  const float* aa_w1 = (const float*)d_in[IX[12]];
  const float* aa_w2 = (const float*)d_in[IX[13]];
  const float* vv_b  = (const float*)d_in[IX[14]];
  const float* vv_w1 = (const float*)d_in[IX[15]];
  const float* vv_w2 = (const float*)d_in[IX[16]];
  const float* gg_w1 = (const float*)d_in[IX[17]];
  const float* gg_w2 = (const float*)d_in[IX[18]];
  const float* kk_s  = (const float*)d_in[IX[19]];
  const float* ka_s  = (const float*)d_in[IX[20]];
  const float* rk_s  = (const float*)d_in[IX[21]];
  const float* W_r   = (const float*)d_in[IX[22]];
  const float* W_k   = (const float*)d_in[IX[23]];
  const float* W_v   = (const float*)d_in[IX[24]];
  const float* W_o   = (const float*)d_in[IX[25]];
  const float* gn_w  = (const float*)d_in[IX[26]];
  const float* gn_b  = (const float*)d_in[IX[27]];

  const size_t NBTC = (size_t)BT * CC;
  dim3 blk(256);
  const int grid4f = (int)(NBTC / 4 / 256);

  const size_t WS_NEED = 7 * NBTC * sizeof(u16);
  float* outF = (float*)d_out;
  if (ws_size < WS_NEED || d_ws == nullptr) {
    zero_out<<<grid4f, blk, 0, stream>>>(outF);
    copy_v0<<<grid4f, blk, 0, stream>>>(v0, outF + NBTC);
    return;
  }

  // Regions: R0=h1/r  R1=Wt(early)/k  R2=v  R3=partY/Wt/ao/h2
  // R4=a/bo/g  R5=w_raw/wd -> partG/Wt(g,o)  R6=mix staging/rw.
  // y (bf16) in d_out v0-slot front half; scal2 + scal4 in its back half.
  u16* W16   = (u16*)d_ws;
  u16* R0 = W16 + 0 * NBTC;
  u16* R1 = W16 + 1 * NBTC;
  u16* R2 = W16 + 2 * NBTC;
  u16* R3 = W16 + 3 * NBTC;
  u16* R4 = W16 + 4 * NBTC;
  u16* R5 = W16 + 5 * NBTC;
  u16* R6 = W16 + 6 * NBTC;
  float* partY = (float*)R3;
  float* partG = (float*)R5;
  u16* ws_y = (u16*)(outF + NBTC);          // bf16 y: front half of v0 slot
  float2* scal = (float2*)(ws_y + NBTC);    // kr/br per (b,t,h): 1 MiB
  float4* scal4 = (float4*)(ws_y + NBTC + (size_t)BT * HH * 4);  // pair scalars

  const int gridMix = (BT * CC) / 256;
  dim3 gM(BT / 128, 2048 / 128);            // (32, 16)

  // ---- w path
  mix_k<<<gridMix, blk, 0, stream>>>(x, xx_w, R6);
  gemm_part_k<<<dim3(32, 2, 8), blk, 0, stream>>>(R6, ww_w1, partY,
      BT, 96, 2048, 256, 128);
  reduce_k<<<(BT * 96 + 255) / 256, blk, 0, stream>>>(partY, R0, BT, 96, 128, 8, 1);
  wt_k<<<dim3(3, 64), blk, 0, stream>>>(ww_w2, R1, 96, 2048);
  mgemm_k<EPI_BIAS_SP><<<gM, blk, 0, stream>>>(R0, R1, nullptr, R5,
      BT, 2048, 96, ww_b, nullptr, nullptr);

  // ---- a path
  mix_k<<<gridMix, blk, 0, stream>>>(x, xx_a, R6);
  gemm_part_k<<<dim3(32, 2, 8), blk, 0, stream>>>(R6, aa_w1, partY,
      BT, 96, 2048, 256, 128);
  reduce_k<<<(BT * 96 + 255) / 256, blk, 0, stream>>>(partY, R0, BT, 96, 128, 8, 0);
  wt_k<<<dim3(3, 64), blk, 0, stream>>>(aa_w2, R1, 96, 2048);
  mgemm_k<EPI_BIAS_SIG><<<gM, blk, 0, stream>>>(R0, R1, nullptr, R4,
      BT, 2048, 96, aa_b, nullptr, nullptr);

  // ---- v path
  mix_k<<<gridMix, blk, 0, stream>>>(x, xx_v, R6);
  wt_k<<<dim3(64, 64), blk, 0, stream>>>(W_v, R1, 2048, 2048);
  mgemm_k<EPI_BF><<<gM, blk, 0, stream>>>(R6, R1, nullptr, R2,
      BT, 2048, 2048, nullptr, nullptr, nullptr);
  gemm_part_k<<<dim3(32, 1, 8), blk, 0, stream>>>(R6, vv_w1, partY,
      BT, 64, 2048, 256, 64);
  reduce_k<<<(BT * 64 + 255) / 256, blk, 0, stream>>>(partY, R0, BT, 64, 64, 8, 0);
  wt_k<<<dim3(2, 64), blk, 0, stream>>>(vv_w2, R1, 64, 2048);
  mgemm_k<EPI_VMIX><<<gM, blk, 0, stream>>>(R0, R1, nullptr, R2,
      BT, 2048, 64, vv_b, R2, v0);

  // ---- k path
  mix_k<<<gridMix, blk, 0, stream>>>(x, xx_k, R6);
  wt_k<<<dim3(64, 64), blk, 0, stream>>>(W_k, R3, 2048, 2048);
  mgemm_k<EPI_BF><<<gM, blk, 0, stream>>>(R6, R3, nullptr, R1,
      BT, 2048, 2048, nullptr, nullptr, nullptr);

  // ---- r path
  mix_k<<<gridMix, blk, 0, stream>>>(x, xx_r, R6);
  wt_k<<<dim3(64, 64), blk, 0, stream>>>(W_r, R3, 2048, 2048);
  mgemm_k<EPI_BF><<<gM, blk, 0, stream>>>(R6, R3, nullptr, R0,
      BT, 2048, 2048, nullptr, nullptr, nullptr);

  // ---- recurrence prep: k(R1),a(R4),r(R0),w_raw(R5) ->
  //      ao(R3), bo(R4), kf(R1), wd(R5), rw(R6), scal
  prep_k<<<BT * HH / 4, blk, 0, stream>>>(R1, R4, R0, R5, kk_s, ka_s,
                                          R3, R4, R1, R5, R6, scal);

  // ---- pair compounding (in place): wd/ao/bo/rw rewritten, scal4 filled
  prep2_k<<<BT / 2 * HH / 4, blk, 0, stream>>>(R5, R3, R4, R6, R1, scal4);

  // ---- recurrence (g=16, 2 steps/iter): rw=R6 wd=R5 k=R1 v=R2 ao=R3 bo=R4
  rec_k<<<256, blk, 0, stream>>>(R6, R5, R1, R2, R3, R4, scal, scal4, ws_y);

  // ---- g path (R5, R3, R4, R6 dead after rec)
  mix_k<<<gridMix, blk, 0, stream>>>(x, xx_g, R6);
  gemm_part_k<<<dim3(32, 4, 2), blk, 0, stream>>>(R6, gg_w1, partG,
      BT, 256, 2048, 1024, 256);
  reduce_k<<<(BT * 256 + 255) / 256, blk, 0, stream>>>(partG, R3, BT, 256, 256, 2, 2);
  wt_k<<<dim3(8, 64), blk, 0, stream>>>(gg_w2, R5, 256, 2048);
  mgemm_k<EPI_BF><<<gM, blk, 0, stream>>>(R3, R5, nullptr, R4,
      BT, 2048, 256, nullptr, nullptr, nullptr);

  // ---- groupnorm + bonus + gate (in place on y)
  gn_k<<<BT * HH / 4, blk, 0, stream>>>(ws_y, R0, R1, R2, R4,
                                        rk_s, gn_w, gn_b);

  // ---- final projection y @ W_o -> fp32 output 0
  wt_k<<<dim3(64, 64), blk, 0, stream>>>(W_o, R5, 2048, 2048);
  mgemm_k<EPI_F32><<<gM, blk, 0, stream>>>(ws_y, R5, outF, nullptr,
      BT, 2048, 2048, nullptr, nullptr, nullptr);

  // ---- v0 passthrough (overwrites y scratch + scal, last)
  copy_v0<<<grid4f, blk, 0, stream>>>(v0, outF + NBTC);
}

// Round 13
// 809.299 us; speedup vs baseline: 1.3989x; 1.0705x over previous
//
#include <hip/hip_runtime.h>
#include <hip/hip_bf16.h>
#include <math.h>

typedef unsigned short u16;
typedef __attribute__((ext_vector_type(4))) unsigned short us4;
typedef __attribute__((ext_vector_type(8))) unsigned short us8;
typedef __attribute__((ext_vector_type(8))) short s8v;   // mfma bf16 operand (4 VGPRs)
typedef __attribute__((ext_vector_type(4))) float f4v;   // mfma accum

#define BB 2
#define TT 1024
#define CC 2048
#define HH 32
#define BT (BB*TT)

// Inputs/outputs fp32. ws intermediates bf16: 7 regions x NBTC u16.
// Weights cvt-transposed to bf16 [N][Kp] just-in-time into dead regions for
// the MFMA GEMMs (Kp = K padded to a multiple of 64; A-side pad cols are
// exact zeros so pad contributions vanish). Recurrence scalars live in the
// back half of d_out's v0 slot.

__device__ __forceinline__ float bf2f(u16 u) {
  return __uint_as_float(((unsigned int)u) << 16);
}
__device__ __forceinline__ u16 f2bf(float f) {
  unsigned int x = __float_as_uint(f);
  x += 0x7fffu + ((x >> 16) & 1u);
  return (u16)(x >> 16);
}

// async global->LDS, 16B per lane; lptr must be the wave-uniform base
// (HW writes base + lane*16 -- m104 semantics).
__device__ __forceinline__ void gload16(const u16* g, u16* l) {
  __builtin_amdgcn_global_load_lds(
      (const __attribute__((address_space(1))) void*)g,
      (__attribute__((address_space(3))) void*)l, 16, 0, 0);
}

// ---------------------------------------------------------------- mix kernel
__global__ __launch_bounds__(256)
void mix_k(const float* __restrict__ x, const float* __restrict__ s,
           u16* __restrict__ out) {
  int idx = blockIdx.x * 256 + threadIdx.x;       // over BT*C
  int c = idx & (CC - 1);
  int t = (idx >> 11) & (TT - 1);
  float xv = x[idx];
  float xp = (t == 0) ? 0.f : x[idx - CC];
  out[idx] = f2bf(xv + (xp - xv) * s[c]);
}

// ---------------------------------------------------------------- weight cvt-transpose
// W fp32 [K][N] -> Wt bf16 [N][Kp] (pitch Kp). 32x32 tiles, 256 threads.
__global__ __launch_bounds__(256)
void wt_k(const float* __restrict__ W, u16* __restrict__ Wt, int K, int N,
          int Kp) {
  __shared__ u16 tile[32][36];
  const int k0 = blockIdx.x * 32, n0 = blockIdx.y * 32;
  const int tid = threadIdx.x;
  const int r = tid >> 3, c4 = (tid & 7) << 2;
  float4 v = *(const float4*)(W + (size_t)(k0 + r) * N + n0 + c4);
  tile[r][c4 + 0] = f2bf(v.x); tile[r][c4 + 1] = f2bf(v.y);
  tile[r][c4 + 2] = f2bf(v.z); tile[r][c4 + 3] = f2bf(v.w);
  __syncthreads();
  ushort4 o;
  o.x = tile[c4 + 0][r]; o.y = tile[c4 + 1][r];
  o.z = tile[c4 + 2][r]; o.w = tile[c4 + 3][r];
  *(ushort4*)(Wt + (size_t)(n0 + r) * Kp + k0 + c4) = o;
}

// ---------------------------------------------------------------- MFMA GEMM
// C[M,N] = A[M,lda](bf16) * Bt[N,ldb](bf16, row n = col n of B), fp32 accum.
// Block tile 128x128, BK=64, 4 waves (2x2), wave tile 64x64 = 4x4 frags.
// Staging: global_load_lds width 16, linear LDS [128][64] u16; both-sides
// XOR swizzle by (row&7) on 16B units (rule #21) -> conflict-free ds_read.
enum { EPI_BF = 0, EPI_F32 = 1, EPI_BIAS_SP = 2, EPI_BIAS_SIG = 3,
       EPI_VMIX = 4 };

template<int EPI>
__global__ __launch_bounds__(256)
void mgemm_k(const u16* __restrict__ A, const u16* __restrict__ Bt,
             float* __restrict__ outF, u16* __restrict__ outB,
             int M, int N, int K, int lda, int ldb,
             const float* __restrict__ bias, const u16* __restrict__ p1,
             const float* __restrict__ p2)
{
  __shared__ alignas(16) u16 As[128 * 64];
  __shared__ alignas(16) u16 Bs[128 * 64];
  const int m0 = blockIdx.x * 128;
  const int n0 = blockIdx.y * 128;
  const int tid = threadIdx.x;
  const int lane = tid & 63;
  const int wid = tid >> 6;
  const int wr = wid >> 1, wc = wid & 1;        // wave quadrant (2x2)
  f4v acc[4][4];
  #pragma unroll
  for (int i = 0; i < 4; ++i)
    #pragma unroll
    for (int j = 0; j < 4; ++j) acc[i][j] = f4v{0.f, 0.f, 0.f, 0.f};

  const int l15 = lane & 15;
  const int lq = lane >> 4;                     // 0..3
  const int nkt = K >> 6;
  for (int kt = 0; kt < nkt; ++kt) {
    const int k0 = kt << 6;
    __syncthreads();                            // prev compute done
    #pragma unroll
    for (int a = 0; a < 4; ++a) {
      const int blkU = (wid * 4 + a) * 64;      // wave-uniform unit base
      const int U = blkU + lane;                // this lane's unit
      const int row = U >> 3;
      const int u = U & 7;
      const int col = ((u ^ (row & 7)) << 3);   // pre-swizzled source col
      gload16(A  + (size_t)(m0 + row) * lda + k0 + col, &As[blkU * 8]);
      gload16(Bt + (size_t)(n0 + row) * ldb + k0 + col, &Bs[blkU * 8]);
    }
    __syncthreads();                            // vmcnt drained -> LDS ready
    #pragma unroll
    for (int h = 0; h < 2; ++h) {
      s8v af[4], bfr[4];
      #pragma unroll
      for (int i = 0; i < 4; ++i) {
        const int row = wr * 64 + i * 16 + l15;
        const int u = (h * 4 + lq) ^ (row & 7); // swizzled read unit
        af[i] = *(const s8v*)&As[row * 64 + u * 8];
      }
      #pragma unroll
      for (int j = 0; j < 4; ++j) {
        const int row = wc * 64 + j * 16 + l15;
        const int u = (h * 4 + lq) ^ (row & 7);
        bfr[j] = *(const s8v*)&Bs[row * 64 + u * 8];
      }
      #pragma unroll
      for (int i = 0; i < 4; ++i)
        #pragma unroll
        for (int j = 0; j < 4; ++j)
          acc[i][j] = __builtin_amdgcn_mfma_f32_16x16x32_bf16(af[i], bfr[j],
                                                              acc[i][j],
                                                              0, 0, 0);
    }
  }
  // C/D layout: col = lane&15, row = (lane>>4)*4 + q  (m89-verified)
  const int rbase = m0 + wr * 64 + (lq << 2);
  const int cbase = n0 + wc * 64 + l15;
  #pragma unroll
  for (int i = 0; i < 4; ++i) {
    #pragma unroll
    for (int j = 0; j < 4; ++j) {
      f4v c = acc[i][j];
      const int col = cbase + j * 16;
      #pragma unroll
      for (int q = 0; q < 4; ++q) {
        const int row = rbase + i * 16 + q;
        const size_t idx = (size_t)row * N + col;
        const float r = c[q];
        if (EPI == EPI_BF) {
          outB[idx] = f2bf(r);
        } else if (EPI == EPI_F32) {
          outF[idx] = r;
        } else if (EPI == EPI_BIAS_SP) {
          float u = bias[col] + r;
          float z = -u;
          float sp = fmaxf(z, 0.f) + log1pf(expf(-fabsf(z)));
          outB[idx] = f2bf(-sp - 0.5f);
        } else if (EPI == EPI_BIAS_SIG) {
          float u = bias[col] + r;
          outB[idx] = f2bf(1.f / (1.f + expf(-u)));
        } else if (EPI == EPI_VMIX) {
          float u = bias[col] + r;
          float sg = 1.f / (1.f + expf(-u));
          float v = bf2f(p1[idx]);
          float v0v = p2[idx];
          outB[idx] = f2bf(v + (v0v - v) * sg);
        }
      }
    }
  }
}

// ---------------------------------------------------------------- SIMT GEMM (skinny w1 paths)
__global__ __launch_bounds__(256)
void gemm_part_k(const u16* __restrict__ A, const float* __restrict__ W,
                 float* __restrict__ outF, int M, int N, int K, int kchunk,
                 int NP)
{
  __shared__ alignas(16) float As[16][68];
  __shared__ alignas(16) float Bs[16][68];
  const int m0 = blockIdx.x * 64;
  const int n0 = blockIdx.y * 64;
  const int kz = blockIdx.z;
  const int k0base = kz * kchunk;
  const int tid = threadIdx.x;
  const int tx = tid & 15, ty = tid >> 4;
  float acc[4][4] = {{0.f}};
  const int a_m = tid >> 2;
  const int a_k = (tid & 3) << 2;
  const int b_k = tid >> 4;
  const int b_n = (tid & 15) << 2;
  const int niters = kchunk >> 4;
  for (int it = 0; it < niters; ++it) {
    const int k0 = k0base + (it << 4);
    float4 av;
    {
      ushort4 u = *(const ushort4*)(A + (size_t)(m0 + a_m) * K + (k0 + a_k));
      av = make_float4(bf2f(u.x), bf2f(u.y), bf2f(u.z), bf2f(u.w));
    }
    float4 bv;
    {
      int gn = n0 + b_n;
      const float* wp = W + (size_t)(k0 + b_k) * N + gn;
      if (gn + 3 < N) {
        bv = *(const float4*)wp;
      } else {
        bv.x = (gn + 0 < N) ? wp[0] : 0.f;
        bv.y = (gn + 1 < N) ? wp[1] : 0.f;
        bv.z = (gn + 2 < N) ? wp[2] : 0.f;
        bv.w = (gn + 3 < N) ? wp[3] : 0.f;
      }
    }
    __syncthreads();
    As[a_k + 0][a_m] = av.x; As[a_k + 1][a_m] = av.y;
    As[a_k + 2][a_m] = av.z; As[a_k + 3][a_m] = av.w;
    Bs[b_k][b_n + 0] = bv.x; Bs[b_k][b_n + 1] = bv.y;
    Bs[b_k][b_n + 2] = bv.z; Bs[b_k][b_n + 3] = bv.w;
    __syncthreads();
    #pragma unroll
    for (int kk = 0; kk < 16; ++kk) {
      float4 a4 = *(const float4*)&As[kk][ty << 2];
      float4 b4 = *(const float4*)&Bs[kk][tx << 2];
      float ar[4] = {a4.x, a4.y, a4.z, a4.w};
      float br[4] = {b4.x, b4.y, b4.z, b4.w};
      #pragma unroll
      for (int i = 0; i < 4; ++i)
        #pragma unroll
        for (int j = 0; j < 4; ++j)
          acc[i][j] = fmaf(ar[i], br[j], acc[i][j]);
    }
  }
  #pragma unroll
  for (int i = 0; i < 4; ++i) {
    int gm = m0 + (ty << 2) + i;
    #pragma unroll
    for (int j = 0; j < 4; ++j) {
      int gn = n0 + (tx << 2) + j;
      if (gn >= N) continue;
      outF[((size_t)kz * M + gm) * NP + gn] = acc[i][j];
    }
  }
}

// ---------------------------------------------------------------- K-split reduce
// out pitch Dp (>= D); pad cols written as EXACT ZEROS (after act) so the
// padded-K MFMA contributes nothing.
__global__ __launch_bounds__(256)
void reduce_k(const float* __restrict__ part, u16* __restrict__ out,
              int M, int D, int NP, int nz, int act, int Dp)
{
  int idx = blockIdx.x * 256 + threadIdx.x;
  if (idx >= M * Dp) return;
  int t = idx / Dp, n = idx - t * Dp;
  float s = 0.f;
  if (n < D) {
    for (int z = 0; z < nz; ++z) s += part[((size_t)z * M + t) * NP + n];
    if (act == 1) s = tanhf(s);
    else if (act == 2) s = 1.f / (1.f + expf(-s));
  }
  out[idx] = f2bf(s);
}

// ---------------------------------------------------------------- recurrence prep
__global__ __launch_bounds__(256)
void prep_k(const u16* __restrict__ k_in, const u16* __restrict__ a_in,
            const u16* __restrict__ r_in, const u16* __restrict__ w_in,
            const float* __restrict__ kk_s, const float* __restrict__ ka_s,
            u16* __restrict__ ao_out, u16* __restrict__ bo_out,
            u16* __restrict__ k_out, u16* __restrict__ wd_out,
            u16* __restrict__ rw_out, float2* __restrict__ scal)
{
  int tid = threadIdx.x;
  int lane = tid & 63;
  int wv = tid >> 6;
  int hidx = blockIdx.x * 4 + wv;               // (b*T+t)*H + h
  int h = hidx & (HH - 1);
  int c = (h << 6) + lane;
  size_t base = ((size_t)hidx << 6) + lane;
  float k = bf2f(k_in[base]);
  float kk = k * kk_s[c];
  float ss = kk * kk;
  for (int off = 32; off; off >>= 1) ss += __shfl_xor(ss, off, 64);
  float kkn = kk / fmaxf(sqrtf(ss), 1e-12f);
  float a = bf2f(a_in[base]);
  float r = bf2f(r_in[base]);
  float kf = k * (1.f + (a - 1.f) * ka_s[c]);
  float wd = expf(-expf(bf2f(w_in[base])));
  float bo = kkn * a;
  ao_out[base] = f2bf(-kkn);
  bo_out[base] = f2bf(bo);
  k_out[base]  = f2bf(kf);
  wd_out[base] = f2bf(wd);
  rw_out[base] = f2bf(wd * r);
  float kr = kf * r, br = bo * r;
  kr += __shfl_xor(kr, 1, 64);  br += __shfl_xor(br, 1, 64);
  kr += __shfl_xor(kr, 2, 64);  br += __shfl_xor(br, 2, 64);
  kr += __shfl_xor(kr, 4, 64);  br += __shfl_xor(br, 4, 64);
  kr += __shfl_xor(kr, 8, 64);  br += __shfl_xor(br, 8, 64);
  kr += __shfl_xor(kr, 16, 64); br += __shfl_xor(br, 16, 64);
  kr += __shfl_xor(kr, 32, 64); br += __shfl_xor(br, 32, 64);
  if (lane == 0) scal[hidx] = make_float2(kr, br);
}

// ---------------------------------------------------------------- pair prep
// Two-step compounding (in place; see R12 notes).
__global__ __launch_bounds__(256)
void prep2_k(u16* __restrict__ wd, u16* __restrict__ ao,
             u16* __restrict__ bo, u16* __restrict__ rw,
             const u16* __restrict__ kf, float4* __restrict__ scal4)
{
  int tid = threadIdx.x;
  int lane = tid & 63;
  int wv = tid >> 6;
  int hpidx = blockIdx.x * 4 + wv;              // over (b, tp, h), h fastest
  int h = hpidx & (HH - 1);
  int btp = hpidx >> 5;
  int tp = btp & (TT / 2 - 1);
  int b = btp >> 9;                             // TT/2 = 512
  size_t be = ((size_t)(b * TT + 2 * tp)) * CC + (h << 6) + lane;
  size_t bodd = be + CC;
  float wd1 = bf2f(wd[be]),  wd2 = bf2f(wd[bodd]);
  float ao2 = bf2f(ao[bodd]), rw2 = bf2f(rw[bodd]);
  float bo1 = bf2f(bo[be]),  k1  = bf2f(kf[be]);
  float cba = bo1 * ao2, ckb = k1 * ao2, crb = bo1 * rw2, crk = k1 * rw2;
  #pragma unroll
  for (int off = 32; off; off >>= 1) {
    cba += __shfl_xor(cba, off, 64);
    ckb += __shfl_xor(ckb, off, 64);
    crb += __shfl_xor(crb, off, 64);
    crk += __shfl_xor(crk, off, 64);
  }
  wd[be]   = f2bf(wd1 * wd2);
  wd[bodd] = f2bf(k1 * wd2);
  ao[bodd] = f2bf(wd1 * ao2);
  bo[be]   = f2bf(bo1 * wd2);
  rw[bodd] = f2bf(wd1 * rw2);
  if (lane == 0) scal4[hpidx] = make_float4(cba, ckb, crb, crk);
}

// ---------------------------------------------------------------- RWKV7 recurrence
// g=16 geometry + 2-step compounding (R12): one iteration advances TWO
// timesteps with a single 4-level butterfly round of 4 interleaved
// reductions (u1,u2,q1,q2) on the same pre-pair state.
__global__ __launch_bounds__(256)
void rec_k(const u16* __restrict__ rw, const u16* __restrict__ wd,
           const u16* __restrict__ kv, const u16* __restrict__ v,
           const u16* __restrict__ ao, const u16* __restrict__ bo,
           const float2* __restrict__ scal, const float4* __restrict__ scal4,
           u16* __restrict__ y)
{
  const int gw = blockIdx.x * 4 + (threadIdx.x >> 6);   // 0..1023
  const int lane = threadIdx.x & 63;
  const int sub = lane & 15;
  const int grp = lane >> 4;
  const int bh = gw >> 4;
  const int rblk = gw & 15;
  const int i = rblk * 4 + grp;
  const int b = bh >> 5, h = bh & (HH - 1);
  const size_t base0 = ((size_t)b * TT) * CC + (h << 6);
  const size_t vecb = base0 + (sub << 2);
  const size_t vb   = base0 + i;
  const int sbase = b * TT * HH + h;
  const int pbase = b * (TT / 2) * HH + h;
  float s0 = 0.f, s1 = 0.f, s2 = 0.f, s3 = 0.f;

  us4 W12, KW1, AO1, WA2, BW1, BO2, RW1, WR2, K2;
  float V1, V2; float2 SE, SO; float4 S4;
#define PLOAD(TP) do {                                                  \
    const size_t be_ = vecb + (size_t)(2 * (TP)) * CC;                  \
    const size_t bo_ = be_ + CC;                                        \
    W12 = *(const us4*)(wd + be_);  KW1 = *(const us4*)(wd + bo_);      \
    AO1 = *(const us4*)(ao + be_);  WA2 = *(const us4*)(ao + bo_);      \
    BW1 = *(const us4*)(bo + be_);  BO2 = *(const us4*)(bo + bo_);      \
    RW1 = *(const us4*)(rw + be_);  WR2 = *(const us4*)(rw + bo_);      \
    K2  = *(const us4*)(kv + bo_);                                      \
    V1 = bf2f(v[vb + (size_t)(2 * (TP)) * CC]);                         \
    V2 = bf2f(v[vb + (size_t)(2 * (TP) + 1) * CC]);                     \
    SE = scal[sbase + (2 * (TP)) * HH];                                 \
    SO = scal[sbase + (2 * (TP) + 1) * HH];                             \
    S4 = scal4[pbase + (TP) * HH];                                      \
  } while (0)

  PLOAD(0);
  for (int tp = 0; tp < TT / 2; ++tp) {
    const float w0 = bf2f(W12[0]), w1 = bf2f(W12[1]),
                w2 = bf2f(W12[2]), w3 = bf2f(W12[3]);
    const float kw0 = bf2f(KW1[0]), kw1_ = bf2f(KW1[1]),
                kw2 = bf2f(KW1[2]), kw3 = bf2f(KW1[3]);
    const float a0 = bf2f(AO1[0]), a1 = bf2f(AO1[1]),
                a2 = bf2f(AO1[2]), a3 = bf2f(AO1[3]);
    const float x0 = bf2f(WA2[0]), x1 = bf2f(WA2[1]),
                x2 = bf2f(WA2[2]), x3 = bf2f(WA2[3]);
    const float bw0 = bf2f(BW1[0]), bw1_ = bf2f(BW1[1]),
                bw2 = bf2f(BW1[2]), bw3 = bf2f(BW1[3]);
    const float b0 = bf2f(BO2[0]), b1 = bf2f(BO2[1]),
                b2 = bf2f(BO2[2]), b3 = bf2f(BO2[3]);
    const float e0 = bf2f(RW1[0]), e1 = bf2f(RW1[1]),
                e2 = bf2f(RW1[2]), e3 = bf2f(RW1[3]);
    const float f0 = bf2f(WR2[0]), f1 = bf2f(WR2[1]),
                f2 = bf2f(WR2[2]), f3 = bf2f(WR2[3]);
    const float k0 = bf2f(K2[0]), k1 = bf2f(K2[1]),
                k2 = bf2f(K2[2]), k3 = bf2f(K2[3]);
    const float v1c = V1, v2c = V2;
    const float kr1 = SE.x, br1 = SE.y, kr2 = SO.x, br2 = SO.y;
    const float cba = S4.x, ckb = S4.y, crb = S4.z, crk = S4.w;
    if (tp + 1 < TT / 2) PLOAD(tp + 1);
    float u1 = fmaf(s3, a3, fmaf(s2, a2, fmaf(s1, a1, s0 * a0)));
    float u2 = fmaf(s3, x3, fmaf(s2, x2, fmaf(s1, x1, s0 * x0)));
    float q1 = fmaf(s3, e3, fmaf(s2, e2, fmaf(s1, e1, s0 * e0)));
    float q2 = fmaf(s3, f3, fmaf(s2, f2, fmaf(s1, f1, s0 * f0)));
    u1 += __shfl_xor(u1, 1, 64);  u2 += __shfl_xor(u2, 1, 64);
    q1 += __shfl_xor(q1, 1, 64);  q2 += __shfl_xor(q2, 1, 64);
    u1 += __shfl_xor(u1, 2, 64);  u2 += __shfl_xor(u2, 2, 64);
    q1 += __shfl_xor(q1, 2, 64);  q2 += __shfl_xor(q2, 2, 64);
    u1 += __shfl_xor(u1, 4, 64);  u2 += __shfl_xor(u2, 4, 64);
    q1 += __shfl_xor(q1, 4, 64);  q2 += __shfl_xor(q2, 4, 64);
    u1 += __shfl_xor(u1, 8, 64);  u2 += __shfl_xor(u2, 8, 64);
    q1 += __shfl_xor(q1, 8, 64);  q2 += __shfl_xor(q2, 8, 64);
    const float sac = fmaf(ckb, v1c, fmaf(cba, u1, u2));
    const float y1 = fmaf(br1, u1, fmaf(kr1, v1c, q1));
    const float y2 = fmaf(br2, sac, fmaf(kr2, v2c,
                       fmaf(crb, u1, fmaf(crk, v1c, q2))));
    s0 = fmaf(v2c, k0, fmaf(v1c, kw0, fmaf(sac, b0, fmaf(u1, bw0, s0 * w0))));
    s1 = fmaf(v2c, k1, fmaf(v1c, kw1_, fmaf(sac, b1, fmaf(u1, bw1_, s1 * w1))));
    s2 = fmaf(v2c, k2, fmaf(v1c, kw2, fmaf(sac, b2, fmaf(u1, bw2, s2 * w2))));
    s3 = fmaf(v2c, k3, fmaf(v1c, kw3, fmaf(sac, b3, fmaf(u1, bw3, s3 * w3))));
    if (sub == 0) {
      y[vb + (size_t)(2 * tp) * CC] = f2bf(y1);
      y[vb + (size_t)(2 * tp + 1) * CC] = f2bf(y2);
    }
  }
#undef PLOAD
}

// ---------------------------------------------------------------- GroupNorm + bonus + gate
__global__ __launch_bounds__(256)
void gn_k(u16* __restrict__ y, const u16* __restrict__ r,
          const u16* __restrict__ k, const u16* __restrict__ v,
          const u16* __restrict__ g, const float* __restrict__ rk_s,
          const float* __restrict__ gn_w, const float* __restrict__ gn_b)
{
  int tid = threadIdx.x, lane = tid & 63, wv = tid >> 6;
  int hidx = blockIdx.x * 4 + wv;
  int h = hidx & (HH - 1);
  int c = (h << 6) + lane;
  size_t base = ((size_t)hidx << 6) + lane;
  float yv = bf2f(y[base]), rv = bf2f(r[base]), kv = bf2f(k[base]);
  float vv = bf2f(v[base]), gv = bf2f(g[base]);
  float bsum = rv * kv * rk_s[c];
  float s1 = yv, s2 = yv * yv;
  for (int off = 32; off; off >>= 1) {
    s1 += __shfl_xor(s1, off, 64);
    s2 += __shfl_xor(s2, off, 64);
    bsum += __shfl_xor(bsum, off, 64);
  }
  float mu = s1 * (1.f / 64.f);
  float var = s2 * (1.f / 64.f) - mu * mu;
  float rstd = rsqrtf(var + 0.00064f);
  float z = (yv - mu) * rstd * gn_w[c] + gn_b[c];
  y[base] = f2bf((z + bsum * vv) * gv);
}

// ---------------------------------------------------------------- helpers
__global__ __launch_bounds__(256)
void copy_v0(const float* __restrict__ v0, float* __restrict__ out) {
  int idx = blockIdx.x * 256 + threadIdx.x;
  ((float4*)out)[idx] = ((const float4*)v0)[idx];
}

__global__ __launch_bounds__(256)
void zero_out(float* __restrict__ out) {
  int idx = blockIdx.x * 256 + threadIdx.x;
  ((float4*)out)[idx] = make_float4(0.f, 0.f, 0.f, 0.f);
}

// ----------------------------------------------------------------
extern "C" void kernel_launch(void* const* d_in, const int* in_sizes, int n_in,
                              void* d_out, int out_size, void* d_ws, size_t ws_size,
                              hipStream_t stream) {
  (void)n_in; (void)out_size;
  const bool dictOrder = (in_sizes[9] == CC);
  int IX[28];
  if (dictOrder) {
    const int m[28] = {0,1,2,3,4,5,6,7, 8,13,14, 9,15,16, 10,17,18, 19,20,
                       11,12,21, 22,23,24,25, 26,27};
    for (int i = 0; i < 28; ++i) IX[i] = m[i];
  } else {
    for (int i = 0; i < 28; ++i) IX[i] = i;
  }
  const float* x     = (const float*)d_in[IX[0]];
  const float* v0    = (const float*)d_in[IX[1]];
  const float* xx_r  = (const float*)d_in[IX[2]];
  const float* xx_w  = (const float*)d_in[IX[3]];
  const float* xx_k  = (const float*)d_in[IX[4]];
  const float* xx_v  = (const float*)d_in[IX[5]];
  const float* xx_a  = (const float*)d_in[IX[6]];
  const float* xx_g  = (const float*)d_in[IX[7]];
  const float* ww_b  = (const float*)d_in[IX[8]];
  const float* ww_w1 = (const float*)d_in[IX[9]];
  const float* ww_w2 = (const float*)d_in[IX[10]];
  const float* aa_b  = (const float*)d_in[IX[11]];
  const float* aa_w1 = (const float*)d_in[IX[12]];
  const float* aa_w2 = (const float*)d_in[IX[13]];
  const float* vv_b  = (const float*)d_in[IX[14]];
  const float* vv_w1 = (const float*)d_in[IX[15]];
  const float* vv_w2 = (const float*)d_in[IX[16]];
  const float* gg_w1 = (const float*)d_in[IX[17]];
  const float* gg_w2 = (const float*)d_in[IX[18]];
  const float* kk_s  = (const float*)d_in[IX[19]];
  const float* ka_s  = (const float*)d_in[IX[20]];
  const float* rk_s  = (const float*)d_in[IX[21]];
  const float* W_r   = (const float*)d_in[IX[22]];
  const float* W_k   = (const float*)d_in[IX[23]];
  const float* W_v   = (const float*)d_in[IX[24]];
  const float* W_o   = (const float*)d_in[IX[25]];
  const float* gn_w  = (const float*)d_in[IX[26]];
  const float* gn_b  = (const float*)d_in[IX[27]];

  const size_t NBTC = (size_t)BT * CC;
  dim3 blk(256);
  const int grid4f = (int)(NBTC / 4 / 256);

  const size_t WS_NEED = 7 * NBTC * sizeof(u16);
  float* outF = (float*)d_out;
  if (ws_size < WS_NEED || d_ws == nullptr) {
    zero_out<<<grid4f, blk, 0, stream>>>(outF);
    copy_v0<<<grid4f, blk, 0, stream>>>(v0, outF + NBTC);
    return;
  }

  // Regions: R0=h1/r  R1=Wt(early)/k  R2=v  R3=partY/Wt/ao/h2
  // R4=a/bo/g  R5=w_raw/wd -> partG/Wt(g,o)  R6=mix staging/rw.
  // y (bf16) in d_out v0-slot front half; scal2 + scal4 in its back half.
  u16* W16   = (u16*)d_ws;
  u16* R0 = W16 + 0 * NBTC;
  u16* R1 = W16 + 1 * NBTC;
  u16* R2 = W16 + 2 * NBTC;
  u16* R3 = W16 + 3 * NBTC;
  u16* R4 = W16 + 4 * NBTC;
  u16* R5 = W16 + 5 * NBTC;
  u16* R6 = W16 + 6 * NBTC;
  float* partY = (float*)R3;
  float* partG = (float*)R5;
  u16* ws_y = (u16*)(outF + NBTC);          // bf16 y: front half of v0 slot
  float2* scal = (float2*)(ws_y + NBTC);    // kr/br per (b,t,h)
  float4* scal4 = (float4*)(ws_y + NBTC + (size_t)BT * HH * 4);  // pair scalars

  const int gridMix = (BT * CC) / 256;
  dim3 gM(BT / 128, 2048 / 128);            // (32, 16)

  // ---- w path (K=96 padded to 128)
  mix_k<<<gridMix, blk, 0, stream>>>(x, xx_w, R6);
  gemm_part_k<<<dim3(32, 2, 8), blk, 0, stream>>>(R6, ww_w1, partY,
      BT, 96, 2048, 256, 128);
  reduce_k<<<(BT * 128) / 256, blk, 0, stream>>>(partY, R0, BT, 96, 128, 8, 1, 128);
  wt_k<<<dim3(3, 64), blk, 0, stream>>>(ww_w2, R1, 96, 2048, 128);
  mgemm_k<EPI_BIAS_SP><<<gM, blk, 0, stream>>>(R0, R1, nullptr, R5,
      BT, 2048, 128, 128, 128, ww_b, nullptr, nullptr);

  // ---- a path (K=96 padded to 128)
  mix_k<<<gridMix, blk, 0, stream>>>(x, xx_a, R6);
  gemm_part_k<<<dim3(32, 2, 8), blk, 0, stream>>>(R6, aa_w1, partY,
      BT, 96, 2048, 256, 128);
  reduce_k<<<(BT * 128) / 256, blk, 0, stream>>>(partY, R0, BT, 96, 128, 8, 0, 128);
  wt_k<<<dim3(3, 64), blk, 0, stream>>>(aa_w2, R1, 96, 2048, 128);
  mgemm_k<EPI_BIAS_SIG><<<gM, blk, 0, stream>>>(R0, R1, nullptr, R4,
      BT, 2048, 128, 128, 128, aa_b, nullptr, nullptr);

  // ---- v path
  mix_k<<<gridMix, blk, 0, stream>>>(x, xx_v, R6);
  wt_k<<<dim3(64, 64), blk, 0, stream>>>(W_v, R1, 2048, 2048, 2048);
  mgemm_k<EPI_BF><<<gM, blk, 0, stream>>>(R6, R1, nullptr, R2,
      BT, 2048, 2048, 2048, 2048, nullptr, nullptr, nullptr);
  gemm_part_k<<<dim3(32, 1, 8), blk, 0, stream>>>(R6, vv_w1, partY,
      BT, 64, 2048, 256, 64);
  reduce_k<<<(BT * 64) / 256, blk, 0, stream>>>(partY, R0, BT, 64, 64, 8, 0, 64);
  wt_k<<<dim3(2, 64), blk, 0, stream>>>(vv_w2, R1, 64, 2048, 64);
  mgemm_k<EPI_VMIX><<<gM, blk, 0, stream>>>(R0, R1, nullptr, R2,
      BT, 2048, 64, 64, 64, vv_b, R2, v0);

  // ---- k path
  mix_k<<<gridMix, blk, 0, stream>>>(x, xx_k, R6);
  wt_k<<<dim3(64, 64), blk, 0, stream>>>(W_k, R3, 2048, 2048, 2048);
  mgemm_k<EPI_BF><<<gM, blk, 0, stream>>>(R6, R3, nullptr, R1,
      BT, 2048, 2048, 2048, 2048, nullptr, nullptr, nullptr);

  // ---- r path
  mix_k<<<gridMix, blk, 0, stream>>>(x, xx_r, R6);
  wt_k<<<dim3(64, 64), blk, 0, stream>>>(W_r, R3, 2048, 2048, 2048);
  mgemm_k<EPI_BF><<<gM, blk, 0, stream>>>(R6, R3, nullptr, R0,
      BT, 2048, 2048, 2048, 2048, nullptr, nullptr, nullptr);

  // ---- recurrence prep: k(R1),a(R4),r(R0),w_raw(R5) ->
  //      ao(R3), bo(R4), kf(R1), wd(R5), rw(R6), scal
  prep_k<<<BT * HH / 4, blk, 0, stream>>>(R1, R4, R0, R5, kk_s, ka_s,
                                          R3, R4, R1, R5, R6, scal);

  // ---- pair compounding (in place): wd/ao/bo/rw rewritten, scal4 filled
  prep2_k<<<BT / 2 * HH / 4, blk, 0, stream>>>(R5, R3, R4, R6, R1, scal4);

  // ---- recurrence (g=16, 2 steps/iter): rw=R6 wd=R5 k=R1 v=R2 ao=R3 bo=R4
  rec_k<<<256, blk, 0, stream>>>(R6, R5, R1, R2, R3, R4, scal, scal4, ws_y);

  // ---- g path (R5, R3, R4, R6 dead after rec)
  mix_k<<<gridMix, blk, 0, stream>>>(x, xx_g, R6);
  gemm_part_k<<<dim3(32, 4, 2), blk, 0, stream>>>(R6, gg_w1, partG,
      BT, 256, 2048, 1024, 256);
  reduce_k<<<(BT * 256) / 256, blk, 0, stream>>>(partG, R3, BT, 256, 256, 2, 2, 256);
  wt_k<<<dim3(8, 64), blk, 0, stream>>>(gg_w2, R5, 256, 2048, 256);
  mgemm_k<EPI_BF><<<gM, blk, 0, stream>>>(R3, R5, nullptr, R4,
      BT, 2048, 256, 256, 256, nullptr, nullptr, nullptr);

  // ---- groupnorm + bonus + gate (in place on y)
  gn_k<<<BT * HH / 4, blk, 0, stream>>>(ws_y, R0, R1, R2, R4,
                                        rk_s, gn_w, gn_b);

  // ---- final projection y @ W_o -> fp32 output 0
  wt_k<<<dim3(64, 64), blk, 0, stream>>>(W_o, R5, 2048, 2048, 2048);
  mgemm_k<EPI_F32><<<gM, blk, 0, stream>>>(ws_y, R5, outF, nullptr,
      BT, 2048, 2048, 2048, 2048, nullptr, nullptr, nullptr);

  // ---- v0 passthrough (overwrites y scratch + scal, last)
  copy_v0<<<grid4f, blk, 0, stream>>>(v0, outF + NBTC);
}